// Round 3
// baseline (750.076 us; speedup 1.0000x reference)
//
#include <hip/hip_runtime.h>
#include <cmath>

#define HIDDEN 2048
#define NH 16
#define NKV 4
#define HD 128
#define SEQ 2048
#define BATCH 2

typedef unsigned short ushort_t;
typedef short bf16x8 __attribute__((ext_vector_type(8)));
typedef float f32x4 __attribute__((ext_vector_type(4)));
typedef ushort_t u16x4 __attribute__((ext_vector_type(4)));

__device__ __forceinline__ ushort_t f2bf(float f) {
    union { float f; unsigned int u; } v; v.f = f;
    unsigned int r = v.u + 0x7fffu + ((v.u >> 16) & 1u);
    return (ushort_t)(r >> 16);
}
__device__ __forceinline__ ushort_t f2bf_trunc(float f) {
    union { float f; unsigned int u; } v; v.f = f;
    return (ushort_t)(v.u >> 16);
}

__device__ __forceinline__ f32x4 mfma16(bf16x8 a, bf16x8 b, f32x4 c) {
    return __builtin_amdgcn_mfma_f32_16x16x32_bf16(a, b, c, 0, 0, 0);
}

// async global -> LDS, 16B per lane. LDS dst is wave-uniform base + lane*16.
__device__ __forceinline__ void load_lds16(const void* g, void* l) {
    __builtin_amdgcn_global_load_lds((const __attribute__((address_space(1))) unsigned int*)g,
                                     (__attribute__((address_space(3))) unsigned int*)l,
                                     16, 0, 0);
}

// ---------------- elementwise fp32 -> bf16 ----------------
__global__ __launch_bounds__(256) void convert_x(const float* __restrict__ x,
                                                 ushort_t* __restrict__ xb, int n4) {
    int g = blockIdx.x * 256 + threadIdx.x;
    if (g >= n4) return;
    float4 v = ((const float4*)x)[g];
    u16x4 o;
    o[0] = f2bf(v.x); o[1] = f2bf(v.y); o[2] = f2bf(v.z); o[3] = f2bf(v.w);
    ((u16x4*)xb)[g] = o;
}

// ---------------- W [K][N] fp32 -> WT [N][K] bf16 (tiled transpose) ----------------
__global__ __launch_bounds__(256) void transpose_w(const float* __restrict__ W,
                                                   ushort_t* __restrict__ WT, int K, int N) {
    __shared__ ushort_t T[64][72];
    const int n0 = blockIdx.x * 64, k0 = blockIdx.y * 64;
    const int t = threadIdx.x;
    for (int idx = t; idx < 64 * 16; idx += 256) {
        int r = idx >> 4, c4 = (idx & 15) << 2;
        float4 v = *(const float4*)&W[(size_t)(k0 + r) * N + n0 + c4];
        T[r][c4 + 0] = f2bf(v.x); T[r][c4 + 1] = f2bf(v.y);
        T[r][c4 + 2] = f2bf(v.z); T[r][c4 + 3] = f2bf(v.w);
    }
    __syncthreads();
    for (int idx = t; idx < 64 * 16; idx += 256) {
        int n = idx >> 4, kg = (idx & 15) << 2;
        u16x4 o;
        o[0] = T[kg + 0][n]; o[1] = T[kg + 1][n];
        o[2] = T[kg + 2][n]; o[3] = T[kg + 3][n];
        *(u16x4*)&WT[(size_t)(n0 + n) * K + k0 + kg] = o;
    }
}

// ---------------- GEMM C = A[M][K] * Bt[N][K]^T + bias, fused epilogues ----------------
// MODE 0: fp32 out + bias (final proj)
// MODE 1: RoPE+scale -> Qr bf16 [B][NH][S][HD]
// MODE 4: fused KV. n0<512: RoPE -> Kr [B][NKV][S][HD]; n0>=512: Vt [B][NKV][HD][S]
template <int MODE>
__global__ __launch_bounds__(256) void gemm_bt(const ushort_t* __restrict__ A,
                                               const ushort_t* __restrict__ Bt,
                                               const float* __restrict__ bias,
                                               const float* __restrict__ bias2,
                                               void* __restrict__ out,
                                               void* __restrict__ out2,
                                               int M, int N, int K,
                                               const int* __restrict__ posids) {
    __shared__ __align__(16) ushort_t As[128 * 32];  // unpadded: global_load_lds layout
    __shared__ __align__(16) ushort_t Bs[128 * 32];
    const int tid = threadIdx.x;
    const int w = tid >> 6, lane = tid & 63, quad = lane >> 4, l16 = lane & 15;
    const int m0 = blockIdx.y * 128, n0 = blockIdx.x * 128;

    f32x4 acc[2][8];
    for (int i = 0; i < 2; i++)
        for (int j = 0; j < 8; j++)
            for (int e = 0; e < 4; e++) acc[i][j][e] = 0.0f;

    const int rr = lane >> 2, cc = (lane & 3) << 3;  // lane -> (row-of-16, 16B chunk)
    const ushort_t* Ag = A + (size_t)(m0 + w * 32 + rr) * K + cc;
    const ushort_t* Bg = Bt + (size_t)(n0 + w * 32 + rr) * K + cc;
    ushort_t* Al0 = &As[(w * 32) * 32];
    ushort_t* Al1 = &As[(w * 32 + 16) * 32];
    ushort_t* Bl0 = &Bs[(w * 32) * 32];
    ushort_t* Bl1 = &Bs[(w * 32 + 16) * 32];

    for (int k0 = 0; k0 < K; k0 += 32) {
        load_lds16(Ag, Al0);
        load_lds16(Ag + (size_t)16 * K, Al1);
        load_lds16(Bg, Bl0);
        load_lds16(Bg + (size_t)16 * K, Bl1);
        Ag += 32; Bg += 32;
        __syncthreads();
        bf16x8 af[2];
#pragma unroll
        for (int i = 0; i < 2; i++)
            af[i] = *(const bf16x8*)&As[(w * 32 + i * 16 + l16) * 32 + quad * 8];
#pragma unroll
        for (int j = 0; j < 8; j++) {
            bf16x8 bf = *(const bf16x8*)&Bs[(j * 16 + l16) * 32 + quad * 8];
#pragma unroll
            for (int i = 0; i < 2; i++) acc[i][j] = mfma16(af[i], bf, acc[i][j]);
        }
        __syncthreads();
    }

    // ---- epilogues ----
    if (MODE == 0) {
        float* O = (float*)out;
#pragma unroll
        for (int i = 0; i < 2; i++)
#pragma unroll
            for (int r = 0; r < 4; r++) {
                int row = m0 + w * 32 + i * 16 + quad * 4 + r;
#pragma unroll
                for (int j = 0; j < 8; j++) {
                    int col = n0 + j * 16 + l16;
                    O[(size_t)row * N + col] = acc[i][j][r] + bias[col];
                }
            }
    } else if (MODE == 1) {
        ushort_t* O = (ushort_t*)out;
        const int h = n0 >> 7;
        const float scale = 0.08838834764831845f;
#pragma unroll
        for (int i = 0; i < 2; i++)
#pragma unroll
            for (int r = 0; r < 4; r++) {
                int row = m0 + w * 32 + i * 16 + quad * 4 + r;  // b*SEQ + s
                int b = row >> 11, s = row & (SEQ - 1);
                float pos = (float)posids[row];
                size_t obase = ((size_t)(b * NH + h) * SEQ + s) * HD;
#pragma unroll
                for (int j = 0; j < 4; j++) {
                    int dl = j * 16 + l16;  // 0..63
                    float x1 = acc[i][j][r] + bias[n0 + dl];
                    float x2 = acc[i][j + 4][r] + bias[n0 + dl + 64];
                    float ang = pos * __expf(-0.21586735246819178f * (float)dl);
                    float sn, cs;
                    __sincosf(ang, &sn, &cs);
                    O[obase + dl]      = f2bf((x1 * cs - x2 * sn) * scale);
                    O[obase + dl + 64] = f2bf((x2 * cs + x1 * sn) * scale);
                }
            }
    } else {  // MODE 4 fused KV
        if (n0 < 512) {  // K path with RoPE
            ushort_t* O = (ushort_t*)out;
            const int h = n0 >> 7;
#pragma unroll
            for (int i = 0; i < 2; i++)
#pragma unroll
                for (int r = 0; r < 4; r++) {
                    int row = m0 + w * 32 + i * 16 + quad * 4 + r;
                    int b = row >> 11, s = row & (SEQ - 1);
                    float pos = (float)posids[row];
                    size_t obase = ((size_t)(b * NKV + h) * SEQ + s) * HD;
#pragma unroll
                    for (int j = 0; j < 4; j++) {
                        int dl = j * 16 + l16;
                        float x1 = acc[i][j][r] + bias[n0 + dl];
                        float x2 = acc[i][j + 4][r] + bias[n0 + dl + 64];
                        float ang = pos * __expf(-0.21586735246819178f * (float)dl);
                        float sn, cs;
                        __sincosf(ang, &sn, &cs);
                        O[obase + dl]      = f2bf(x1 * cs - x2 * sn);
                        O[obase + dl + 64] = f2bf(x2 * cs + x1 * sn);
                    }
                }
        } else {  // V path, transposed store
            ushort_t* O = (ushort_t*)out2;
            const int n0v = n0 - 512;
            const int h = n0v >> 7;
#pragma unroll
            for (int i = 0; i < 2; i++)
#pragma unroll
                for (int r = 0; r < 4; r++) {
                    int row = m0 + w * 32 + i * 16 + quad * 4 + r;
                    int b = row >> 11, s = row & (SEQ - 1);
#pragma unroll
                    for (int j = 0; j < 8; j++) {
                        int d = (n0v & 127) + j * 16 + l16;  // 0..127 within head
                        float v = acc[i][j][r] + bias2[n0v + j * 16 + l16];
                        O[((size_t)(b * NKV + h) * HD + d) * SEQ + s] = f2bf(v);
                    }
                }
        }
    }
}

// ---------------- causal GQA flash attention, BARRIER-FREE ----------------
// Qr [B][NH][S][HD], Kr [B][NKV][S][HD], Vt [B][NKV][HD][S] -> Attn bf16 [B*S][HIDDEN]
// Fixed-reference softmax (m=0): scores bounded |s| <~ 9.4, exp() safe in fp32.
// K/V MFMA B-fragments are contiguous 16B in their layouts -> read straight from
// global (L1/L2 serve the 4x intra-block reuse). No __syncthreads anywhere; only
// per-wave LDS for the P C-layout -> A-layout transform.
__global__ __launch_bounds__(256) void flash(const ushort_t* __restrict__ Qr,
                                             const ushort_t* __restrict__ Kr,
                                             const ushort_t* __restrict__ Vt,
                                             ushort_t* __restrict__ Attn) {
    __shared__ __align__(16) ushort_t Ps[4 * 16 * 72];
    const int tid = threadIdx.x;
    const int w = tid >> 6, lane = tid & 63, quad = lane >> 4, l16 = lane & 15;
    const int qt = (gridDim.x - 1) - blockIdx.x;  // longest blocks first
    const int h = blockIdx.y, b = blockIdx.z;
    const int hkv = h >> 2;
    const int q0 = qt * 64;
    const ushort_t* Kg = Kr + ((size_t)(b * NKV + hkv) * SEQ) * HD;
    const ushort_t* Vg = Vt + ((size_t)(b * NKV + hkv) * HD) * SEQ;

    // Q fragments in registers (A-operand layout, 4 k-chunks of 32)
    bf16x8 aq[4];
    {
        const size_t qrow = ((size_t)(b * NH + h) * SEQ + q0 + w * 16 + l16) * HD;
#pragma unroll
        for (int kc = 0; kc < 4; kc++)
            aq[kc] = *(const bf16x8*)&Qr[qrow + kc * 32 + quad * 8];
    }

    f32x4 o[8];
#pragma unroll
    for (int j = 0; j < 8; j++)
#pragma unroll
        for (int e = 0; e < 4; e++) o[j][e] = 0.0f;
    f32x4 ls;  // row sums via MFMA vs all-ones B
    for (int e = 0; e < 4; e++) ls[e] = 0.0f;
    bf16x8 ones;
#pragma unroll
    for (int e = 0; e < 8; e++) ones[e] = (short)0x3F80;  // bf16 1.0

    ushort_t* Pw = &Ps[w * 16 * 72];

    for (int kt = 0; kt <= qt; kt++) {
        const int kv0 = kt * 64;

        // QK^T: B-fragments straight from global (16 rows x 16B per instr)
        f32x4 sa[4];
#pragma unroll
        for (int nt = 0; nt < 4; nt++)
#pragma unroll
            for (int e = 0; e < 4; e++) sa[nt][e] = 0.0f;
#pragma unroll
        for (int kc = 0; kc < 4; kc++) {
#pragma unroll
            for (int nt = 0; nt < 4; nt++) {
                bf16x8 bk = *(const bf16x8*)&Kg[(size_t)(kv0 + nt * 16 + l16) * HD +
                                                kc * 32 + quad * 8];
                sa[nt] = mfma16(aq[kc], bk, sa[nt]);
            }
        }

        if (kt == qt) {
#pragma unroll
            for (int nt = 0; nt < 4; nt++)
#pragma unroll
                for (int r = 0; r < 4; r++) {
                    int kvg = kv0 + nt * 16 + l16;
                    int qg = q0 + w * 16 + quad * 4 + r;
                    if (kvg > qg) sa[nt][r] = -1e30f;
                }
        }

        // P = exp(s), bf16-truncate, per-wave LDS round-trip (C-layout -> A-layout)
#pragma unroll
        for (int nt = 0; nt < 4; nt++)
#pragma unroll
            for (int r = 0; r < 4; r++)
                Pw[(quad * 4 + r) * 72 + nt * 16 + l16] = f2bf_trunc(__expf(sa[nt][r]));

        // PV: V^T B-fragments straight from global
#pragma unroll
        for (int kc = 0; kc < 2; kc++) {
            bf16x8 ap = *(const bf16x8*)&Pw[l16 * 72 + kc * 32 + quad * 8];
            ls = mfma16(ap, ones, ls);  // row sums
#pragma unroll
            for (int j = 0; j < 8; j++) {
                bf16x8 bv = *(const bf16x8*)&Vg[(size_t)(j * 16 + l16) * SEQ +
                                                kv0 + kc * 32 + quad * 8];
                o[j] = mfma16(ap, bv, o[j]);
            }
        }
    }

#pragma unroll
    for (int r = 0; r < 4; r++) {
        float inv = 1.0f / ls[r];
        int row = b * SEQ + q0 + w * 16 + quad * 4 + r;
        size_t obase = (size_t)row * HIDDEN + h * HD;
#pragma unroll
        for (int j = 0; j < 8; j++) Attn[obase + j * 16 + l16] = f2bf(o[j][r] * inv);
    }
}

extern "C" void kernel_launch(void* const* d_in, const int* in_sizes, int n_in,
                              void* d_out, int out_size, void* d_ws, size_t ws_size,
                              hipStream_t stream) {
    const float* hs = (const float*)d_in[0];
    const int* posids = (const int*)d_in[1];
    const float* Wq = (const float*)d_in[2];
    const float* bq = (const float*)d_in[3];
    const float* Wk = (const float*)d_in[4];
    const float* bk = (const float*)d_in[5];
    const float* Wv = (const float*)d_in[6];
    const float* bv = (const float*)d_in[7];
    const float* Wo = (const float*)d_in[8];
    const float* bo = (const float*)d_in[9];
    float* out = (float*)d_out;

    char* ws = (char*)d_ws;
    size_t off = 0;
    auto alloc = [&](size_t bytes) {
        char* p = ws + off;
        off += (bytes + 255) & ~(size_t)255;
        return p;
    };
    ushort_t* Xb   = (ushort_t*)alloc(4096ull * 2048 * 2);
    ushort_t* WqT  = (ushort_t*)alloc(2048ull * 2048 * 2);
    ushort_t* WkvT = (ushort_t*)alloc(1024ull * 2048 * 2);  // rows 0..511 = Wk^T, 512..1023 = Wv^T
    ushort_t* WoT  = (ushort_t*)alloc(2048ull * 2048 * 2);
    ushort_t* Qr   = (ushort_t*)alloc((size_t)BATCH * NH * SEQ * HD * 2);
    ushort_t* Kr   = (ushort_t*)alloc((size_t)BATCH * NKV * SEQ * HD * 2);
    ushort_t* Vtr  = (ushort_t*)alloc((size_t)BATCH * NKV * HD * SEQ * 2);
    ushort_t* Attn = (ushort_t*)alloc(4096ull * 2048 * 2);

    convert_x<<<4096 * 2048 / 4 / 256, 256, 0, stream>>>(hs, Xb, 4096 * 2048 / 4);
    transpose_w<<<dim3(2048 / 64, 2048 / 64), 256, 0, stream>>>(Wq, WqT, 2048, 2048);
    transpose_w<<<dim3(512 / 64, 2048 / 64), 256, 0, stream>>>(Wk, WkvT, 2048, 512);
    transpose_w<<<dim3(512 / 64, 2048 / 64), 256, 0, stream>>>(Wv, WkvT + 512ull * 2048, 2048, 512);
    transpose_w<<<dim3(2048 / 64, 2048 / 64), 256, 0, stream>>>(Wo, WoT, 2048, 2048);

    gemm_bt<1><<<dim3(16, 32), 256, 0, stream>>>(Xb, WqT, bq, nullptr, Qr, nullptr,
                                                 4096, 2048, 2048, posids);
    gemm_bt<4><<<dim3(8, 32), 256, 0, stream>>>(Xb, WkvT, bk, bv, Kr, Vtr,
                                                4096, 1024, 2048, posids);

    flash<<<dim3(SEQ / 64, NH, BATCH), 256, 0, stream>>>(Qr, Kr, Vtr, Attn);

    gemm_bt<0><<<dim3(16, 32), 256, 0, stream>>>(Attn, WoT, bo, nullptr, out, nullptr,
                                                 4096, 2048, 2048, nullptr);
}

// Round 4
// 411.499 us; speedup vs baseline: 1.8228x; 1.8228x over previous
//
#include <hip/hip_runtime.h>
#include <cmath>

#define HIDDEN 2048
#define NH 16
#define NKV 4
#define HD 128
#define SEQ 2048
#define BATCH 2

typedef unsigned short ushort_t;
typedef short bf16x8 __attribute__((ext_vector_type(8)));
typedef float f32x4 __attribute__((ext_vector_type(4)));
typedef ushort_t u16x4 __attribute__((ext_vector_type(4)));

__device__ __forceinline__ ushort_t f2bf(float f) {
    union { float f; unsigned int u; } v; v.f = f;
    unsigned int r = v.u + 0x7fffu + ((v.u >> 16) & 1u);
    return (ushort_t)(r >> 16);
}
__device__ __forceinline__ ushort_t f2bf_trunc(float f) {
    union { float f; unsigned int u; } v; v.f = f;
    return (ushort_t)(v.u >> 16);
}

__device__ __forceinline__ f32x4 mfma16(bf16x8 a, bf16x8 b, f32x4 c) {
    return __builtin_amdgcn_mfma_f32_16x16x32_bf16(a, b, c, 0, 0, 0);
}

// async global -> LDS, 16B per lane. LDS dst is wave-uniform base + lane*16.
__device__ __forceinline__ void load_lds16(const void* g, void* l) {
    __builtin_amdgcn_global_load_lds((const __attribute__((address_space(1))) unsigned int*)g,
                                     (__attribute__((address_space(3))) unsigned int*)l,
                                     16, 0, 0);
}

// ---------------- elementwise fp32 -> bf16 ----------------
__global__ __launch_bounds__(256) void convert_x(const float* __restrict__ x,
                                                 ushort_t* __restrict__ xb, int n4) {
    int g = blockIdx.x * 256 + threadIdx.x;
    if (g >= n4) return;
    float4 v = ((const float4*)x)[g];
    u16x4 o;
    o[0] = f2bf(v.x); o[1] = f2bf(v.y); o[2] = f2bf(v.z); o[3] = f2bf(v.w);
    ((u16x4*)xb)[g] = o;
}

// ---------------- W [K][N] fp32 -> WT [N][K] bf16 (tiled transpose) ----------------
__global__ __launch_bounds__(256) void transpose_w(const float* __restrict__ W,
                                                   ushort_t* __restrict__ WT, int K, int N) {
    __shared__ ushort_t T[64][72];
    const int n0 = blockIdx.x * 64, k0 = blockIdx.y * 64;
    const int t = threadIdx.x;
    for (int idx = t; idx < 64 * 16; idx += 256) {
        int r = idx >> 4, c4 = (idx & 15) << 2;
        float4 v = *(const float4*)&W[(size_t)(k0 + r) * N + n0 + c4];
        T[r][c4 + 0] = f2bf(v.x); T[r][c4 + 1] = f2bf(v.y);
        T[r][c4 + 2] = f2bf(v.z); T[r][c4 + 3] = f2bf(v.w);
    }
    __syncthreads();
    for (int idx = t; idx < 64 * 16; idx += 256) {
        int n = idx >> 4, kg = (idx & 15) << 2;
        u16x4 o;
        o[0] = T[kg + 0][n]; o[1] = T[kg + 1][n];
        o[2] = T[kg + 2][n]; o[3] = T[kg + 3][n];
        *(u16x4*)&WT[(size_t)(n0 + n) * K + k0 + kg] = o;
    }
}

// ---------------- GEMM C = A[M][K] * Bt[N][K]^T + bias, fused epilogues ----------------
// MODE 0: fp32 out + bias (final proj)
// MODE 1: RoPE+scale -> Qr bf16 [B][NH][S][HD]
// MODE 4: fused KV. n0<512: RoPE -> Kr [B][NKV][S][HD]; n0>=512: Vt [B][NKV][HD][S]
template <int MODE>
__global__ __launch_bounds__(256) void gemm_bt(const ushort_t* __restrict__ A,
                                               const ushort_t* __restrict__ Bt,
                                               const float* __restrict__ bias,
                                               const float* __restrict__ bias2,
                                               void* __restrict__ out,
                                               void* __restrict__ out2,
                                               int M, int N, int K,
                                               const int* __restrict__ posids) {
    __shared__ __align__(16) ushort_t As[128 * 32];  // unpadded: global_load_lds layout
    __shared__ __align__(16) ushort_t Bs[128 * 32];
    const int tid = threadIdx.x;
    const int w = tid >> 6, lane = tid & 63, quad = lane >> 4, l16 = lane & 15;
    const int m0 = blockIdx.y * 128, n0 = blockIdx.x * 128;

    f32x4 acc[2][8];
    for (int i = 0; i < 2; i++)
        for (int j = 0; j < 8; j++)
            for (int e = 0; e < 4; e++) acc[i][j][e] = 0.0f;

    const int rr = lane >> 2, cc = (lane & 3) << 3;  // lane -> (row-of-16, 16B chunk)
    const ushort_t* Ag = A + (size_t)(m0 + w * 32 + rr) * K + cc;
    const ushort_t* Bg = Bt + (size_t)(n0 + w * 32 + rr) * K + cc;
    ushort_t* Al0 = &As[(w * 32) * 32];
    ushort_t* Al1 = &As[(w * 32 + 16) * 32];
    ushort_t* Bl0 = &Bs[(w * 32) * 32];
    ushort_t* Bl1 = &Bs[(w * 32 + 16) * 32];

    for (int k0 = 0; k0 < K; k0 += 32) {
        load_lds16(Ag, Al0);
        load_lds16(Ag + (size_t)16 * K, Al1);
        load_lds16(Bg, Bl0);
        load_lds16(Bg + (size_t)16 * K, Bl1);
        Ag += 32; Bg += 32;
        __syncthreads();
        bf16x8 af[2];
#pragma unroll
        for (int i = 0; i < 2; i++)
            af[i] = *(const bf16x8*)&As[(w * 32 + i * 16 + l16) * 32 + quad * 8];
#pragma unroll
        for (int j = 0; j < 8; j++) {
            bf16x8 bf = *(const bf16x8*)&Bs[(j * 16 + l16) * 32 + quad * 8];
#pragma unroll
            for (int i = 0; i < 2; i++) acc[i][j] = mfma16(af[i], bf, acc[i][j]);
        }
        __syncthreads();
    }

    // ---- epilogues ----
    if (MODE == 0) {
        float* O = (float*)out;
#pragma unroll
        for (int i = 0; i < 2; i++)
#pragma unroll
            for (int r = 0; r < 4; r++) {
                int row = m0 + w * 32 + i * 16 + quad * 4 + r;
#pragma unroll
                for (int j = 0; j < 8; j++) {
                    int col = n0 + j * 16 + l16;
                    O[(size_t)row * N + col] = acc[i][j][r] + bias[col];
                }
            }
    } else if (MODE == 1) {
        ushort_t* O = (ushort_t*)out;
        const int h = n0 >> 7;
        const float scale = 0.08838834764831845f;
#pragma unroll
        for (int i = 0; i < 2; i++)
#pragma unroll
            for (int r = 0; r < 4; r++) {
                int row = m0 + w * 32 + i * 16 + quad * 4 + r;  // b*SEQ + s
                int b = row >> 11, s = row & (SEQ - 1);
                float pos = (float)posids[row];
                size_t obase = ((size_t)(b * NH + h) * SEQ + s) * HD;
#pragma unroll
                for (int j = 0; j < 4; j++) {
                    int dl = j * 16 + l16;  // 0..63
                    float x1 = acc[i][j][r] + bias[n0 + dl];
                    float x2 = acc[i][j + 4][r] + bias[n0 + dl + 64];
                    float ang = pos * __expf(-0.21586735246819178f * (float)dl);
                    float sn, cs;
                    __sincosf(ang, &sn, &cs);
                    O[obase + dl]      = f2bf((x1 * cs - x2 * sn) * scale);
                    O[obase + dl + 64] = f2bf((x2 * cs + x1 * sn) * scale);
                }
            }
    } else {  // MODE 4 fused KV
        if (n0 < 512) {  // K path with RoPE
            ushort_t* O = (ushort_t*)out;
            const int h = n0 >> 7;
#pragma unroll
            for (int i = 0; i < 2; i++)
#pragma unroll
                for (int r = 0; r < 4; r++) {
                    int row = m0 + w * 32 + i * 16 + quad * 4 + r;
                    int b = row >> 11, s = row & (SEQ - 1);
                    float pos = (float)posids[row];
                    size_t obase = ((size_t)(b * NKV + h) * SEQ + s) * HD;
#pragma unroll
                    for (int j = 0; j < 4; j++) {
                        int dl = j * 16 + l16;
                        float x1 = acc[i][j][r] + bias[n0 + dl];
                        float x2 = acc[i][j + 4][r] + bias[n0 + dl + 64];
                        float ang = pos * __expf(-0.21586735246819178f * (float)dl);
                        float sn, cs;
                        __sincosf(ang, &sn, &cs);
                        O[obase + dl]      = f2bf(x1 * cs - x2 * sn);
                        O[obase + dl + 64] = f2bf(x2 * cs + x1 * sn);
                    }
                }
        } else {  // V path, transposed store
            ushort_t* O = (ushort_t*)out2;
            const int n0v = n0 - 512;
            const int h = n0v >> 7;
#pragma unroll
            for (int i = 0; i < 2; i++)
#pragma unroll
                for (int r = 0; r < 4; r++) {
                    int row = m0 + w * 32 + i * 16 + quad * 4 + r;
                    int b = row >> 11, s = row & (SEQ - 1);
#pragma unroll
                    for (int j = 0; j < 8; j++) {
                        int d = (n0v & 127) + j * 16 + l16;  // 0..127 within head
                        float v = acc[i][j][r] + bias2[n0v + j * 16 + l16];
                        O[((size_t)(b * NKV + h) * HD + d) * SEQ + s] = f2bf(v);
                    }
                }
        }
    }
}

// ---------------- causal GQA flash attention, double-buffered LDS staging ----------------
// Qr [B][NH][S][HD], Kr [B][NKV][S][HD], Vt [B][NKV][HD][S] -> Attn bf16 [B*S][HIDDEN]
// Fixed-reference softmax (m=0): scores bounded |s| <~ 9.4, exp() safe in fp32.
// K/V staged via async global_load_lds (width 16) in k-chunked layout; tile kt+1
// prefetches while tile kt computes; ONE barrier per iteration.
__global__ __launch_bounds__(256) void flash(const ushort_t* __restrict__ Qr,
                                             const ushort_t* __restrict__ Kr,
                                             const ushort_t* __restrict__ Vt,
                                             ushort_t* __restrict__ Attn) {
    // Ks: [buf2][kc4][row64][col32], Vs: [buf2][kc2][row128][col32], Ps: per-wave 16x72
    __shared__ __align__(16) ushort_t Ksh[2 * 4 * 64 * 32];
    __shared__ __align__(16) ushort_t Vsh[2 * 2 * 128 * 32];
    __shared__ __align__(16) ushort_t Ps[4 * 16 * 72];
    const int tid = threadIdx.x;
    const int w = tid >> 6, lane = tid & 63, quad = lane >> 4, l16 = lane & 15;
    const int qt = (gridDim.x - 1) - blockIdx.x;  // longest blocks first
    const int h = blockIdx.y, b = blockIdx.z;
    const int hkv = h >> 2;
    const int q0 = qt * 64;
    const ushort_t* Kg = Kr + ((size_t)(b * NKV + hkv) * SEQ) * HD;
    const ushort_t* Vg = Vt + ((size_t)(b * NKV + hkv) * HD) * SEQ;

    // per-lane constant staging addresses
    // K: wave w stages chunk kc=w (cols w*32..w*32+31), rows via 4 calls of 16
    const ushort_t* kst = Kg + (size_t)(lane >> 2) * HD + w * 32 + (lane & 3) * 8;
    // V: wave w stages chunk kc=w>>1, row-half (w&1)*64, 4 calls of 16 rows
    const ushort_t* vst = Vg + (size_t)((w & 1) * 64 + (lane >> 2)) * SEQ +
                          (w >> 1) * 32 + (lane & 3) * 8;
    ushort_t* ksl = Ksh + w * 2048;                             // + buf*8192, + call*512
    ushort_t* vsl = Vsh + (w >> 1) * 4096 + (w & 1) * 2048;     // + buf*8192, + call*512

    auto stage = [&](int bi, int kv0) {
        const ushort_t* gk = kst + (size_t)kv0 * HD;
        ushort_t* lk = ksl + bi * 8192;
        load_lds16(gk, lk);
        load_lds16(gk + (size_t)16 * HD, lk + 512);
        load_lds16(gk + (size_t)32 * HD, lk + 1024);
        load_lds16(gk + (size_t)48 * HD, lk + 1536);
        const ushort_t* gv = vst + kv0;
        ushort_t* lv = vsl + bi * 8192;
        load_lds16(gv, lv);
        load_lds16(gv + (size_t)16 * SEQ, lv + 512);
        load_lds16(gv + (size_t)32 * SEQ, lv + 1024);
        load_lds16(gv + (size_t)48 * SEQ, lv + 1536);
    };

    // Q fragments in registers (A-operand layout, 4 k-chunks of 32)
    bf16x8 aq[4];
    {
        const size_t qrow = ((size_t)(b * NH + h) * SEQ + q0 + w * 16 + l16) * HD;
#pragma unroll
        for (int kc = 0; kc < 4; kc++)
            aq[kc] = *(const bf16x8*)&Qr[qrow + kc * 32 + quad * 8];
    }

    f32x4 o[8];
#pragma unroll
    for (int j = 0; j < 8; j++)
#pragma unroll
        for (int e = 0; e < 4; e++) o[j][e] = 0.0f;
    f32x4 ls;  // row sums via MFMA vs all-ones B
    for (int e = 0; e < 4; e++) ls[e] = 0.0f;
    bf16x8 ones;
#pragma unroll
    for (int e = 0; e < 8; e++) ones[e] = (short)0x3F80;  // bf16 1.0

    ushort_t* Pw = &Ps[w * 16 * 72];

    stage(0, 0);
    __syncthreads();  // buf0 staged (vmcnt drain is part of barrier semantics)

    for (int kt = 0; kt <= qt; kt++) {
        const int kv0 = kt * 64;
        const int cur = kt & 1;
        if (kt < qt) stage(cur ^ 1, kv0 + 64);  // async prefetch next tile

        const ushort_t* Kb = Ksh + cur * 8192;
        const ushort_t* Vb = Vsh + cur * 8192;

        // QK^T
        f32x4 sa[4];
#pragma unroll
        for (int nt = 0; nt < 4; nt++)
#pragma unroll
            for (int e = 0; e < 4; e++) sa[nt][e] = 0.0f;
#pragma unroll
        for (int kc = 0; kc < 4; kc++) {
#pragma unroll
            for (int nt = 0; nt < 4; nt++) {
                bf16x8 bk = *(const bf16x8*)&Kb[kc * 2048 + (nt * 16 + l16) * 32 + quad * 8];
                sa[nt] = mfma16(aq[kc], bk, sa[nt]);
            }
        }

        if (kt == qt) {
#pragma unroll
            for (int nt = 0; nt < 4; nt++)
#pragma unroll
                for (int r = 0; r < 4; r++) {
                    int kvg = kv0 + nt * 16 + l16;
                    int qg = q0 + w * 16 + quad * 4 + r;
                    if (kvg > qg) sa[nt][r] = -1e30f;
                }
        }

        // P = exp(s), bf16-truncate, per-wave LDS round-trip (C-layout -> A-layout)
#pragma unroll
        for (int nt = 0; nt < 4; nt++)
#pragma unroll
            for (int r = 0; r < 4; r++)
                Pw[(quad * 4 + r) * 72 + nt * 16 + l16] = f2bf_trunc(__expf(sa[nt][r]));

        // PV
#pragma unroll
        for (int kc = 0; kc < 2; kc++) {
            bf16x8 ap = *(const bf16x8*)&Pw[l16 * 72 + kc * 32 + quad * 8];
            ls = mfma16(ap, ones, ls);  // row sums
#pragma unroll
            for (int j = 0; j < 8; j++) {
                bf16x8 bv = *(const bf16x8*)&Vb[kc * 4096 + (j * 16 + l16) * 32 + quad * 8];
                o[j] = mfma16(ap, bv, o[j]);
            }
        }
        __syncthreads();  // drains prefetch (had whole compute phase) + guards buffer reuse
    }

#pragma unroll
    for (int r = 0; r < 4; r++) {
        float inv = 1.0f / ls[r];
        int row = b * SEQ + q0 + w * 16 + quad * 4 + r;
        size_t obase = (size_t)row * HIDDEN + h * HD;
#pragma unroll
        for (int j = 0; j < 8; j++) Attn[obase + j * 16 + l16] = f2bf(o[j][r] * inv);
    }
}

extern "C" void kernel_launch(void* const* d_in, const int* in_sizes, int n_in,
                              void* d_out, int out_size, void* d_ws, size_t ws_size,
                              hipStream_t stream) {
    const float* hs = (const float*)d_in[0];
    const int* posids = (const int*)d_in[1];
    const float* Wq = (const float*)d_in[2];
    const float* bq = (const float*)d_in[3];
    const float* Wk = (const float*)d_in[4];
    const float* bk = (const float*)d_in[5];
    const float* Wv = (const float*)d_in[6];
    const float* bv = (const float*)d_in[7];
    const float* Wo = (const float*)d_in[8];
    const float* bo = (const float*)d_in[9];
    float* out = (float*)d_out;

    char* ws = (char*)d_ws;
    size_t off = 0;
    auto alloc = [&](size_t bytes) {
        char* p = ws + off;
        off += (bytes + 255) & ~(size_t)255;
        return p;
    };
    ushort_t* Xb   = (ushort_t*)alloc(4096ull * 2048 * 2);
    ushort_t* WqT  = (ushort_t*)alloc(2048ull * 2048 * 2);
    ushort_t* WkvT = (ushort_t*)alloc(1024ull * 2048 * 2);  // rows 0..511 = Wk^T, 512..1023 = Wv^T
    ushort_t* WoT  = (ushort_t*)alloc(2048ull * 2048 * 2);
    ushort_t* Qr   = (ushort_t*)alloc((size_t)BATCH * NH * SEQ * HD * 2);
    ushort_t* Kr   = (ushort_t*)alloc((size_t)BATCH * NKV * SEQ * HD * 2);
    ushort_t* Vtr  = (ushort_t*)alloc((size_t)BATCH * NKV * HD * SEQ * 2);
    ushort_t* Attn = (ushort_t*)alloc(4096ull * 2048 * 2);

    convert_x<<<4096 * 2048 / 4 / 256, 256, 0, stream>>>(hs, Xb, 4096 * 2048 / 4);
    transpose_w<<<dim3(2048 / 64, 2048 / 64), 256, 0, stream>>>(Wq, WqT, 2048, 2048);
    transpose_w<<<dim3(512 / 64, 2048 / 64), 256, 0, stream>>>(Wk, WkvT, 2048, 512);
    transpose_w<<<dim3(512 / 64, 2048 / 64), 256, 0, stream>>>(Wv, WkvT + 512ull * 2048, 2048, 512);
    transpose_w<<<dim3(2048 / 64, 2048 / 64), 256, 0, stream>>>(Wo, WoT, 2048, 2048);

    gemm_bt<1><<<dim3(16, 32), 256, 0, stream>>>(Xb, WqT, bq, nullptr, Qr, nullptr,
                                                 4096, 2048, 2048, posids);
    gemm_bt<4><<<dim3(8, 32), 256, 0, stream>>>(Xb, WkvT, bk, bv, Kr, Vtr,
                                                4096, 1024, 2048, posids);

    flash<<<dim3(SEQ / 64, NH, BATCH), 256, 0, stream>>>(Qr, Kr, Vtr, Attn);

    gemm_bt<0><<<dim3(16, 32), 256, 0, stream>>>(Attn, WoT, bo, nullptr, out, nullptr,
                                                 4096, 2048, 2048, nullptr);
}

// Round 5
// 378.896 us; speedup vs baseline: 1.9796x; 1.0860x over previous
//
#include <hip/hip_runtime.h>
#include <cmath>

#define HIDDEN 2048
#define NH 16
#define NKV 4
#define HD 128
#define SEQ 2048
#define BATCH 2

typedef unsigned short ushort_t;
typedef short bf16x8 __attribute__((ext_vector_type(8)));
typedef float f32x4 __attribute__((ext_vector_type(4)));
typedef ushort_t u16x4 __attribute__((ext_vector_type(4)));

__device__ __forceinline__ ushort_t f2bf(float f) {
    union { float f; unsigned int u; } v; v.f = f;
    unsigned int r = v.u + 0x7fffu + ((v.u >> 16) & 1u);
    return (ushort_t)(r >> 16);
}
__device__ __forceinline__ ushort_t f2bf_trunc(float f) {
    union { float f; unsigned int u; } v; v.f = f;
    return (ushort_t)(v.u >> 16);
}

__device__ __forceinline__ f32x4 mfma16(bf16x8 a, bf16x8 b, f32x4 c) {
    return __builtin_amdgcn_mfma_f32_16x16x32_bf16(a, b, c, 0, 0, 0);
}

// async global -> LDS, 16B per lane. LDS dst is wave-uniform base + lane*16.
__device__ __forceinline__ void load_lds16(const void* g, void* l) {
    __builtin_amdgcn_global_load_lds((const __attribute__((address_space(1))) unsigned int*)g,
                                     (__attribute__((address_space(3))) unsigned int*)l,
                                     16, 0, 0);
}

// Bank-swizzle scheme for [rows x 32shorts] tiles staged via global_load_lds:
// 16B-chunk c of row p lives at chunk-position cp = c ^ ((p>>1)&3).
// Staging lane l (p=l>>2, cp=l&3) therefore loads global chunk (l&3)^((l>>3)&3).
// Reader of chunk q at row r uses position q^((r>>1)&3). -> 2-way bank access (free).

// ---------------- elementwise fp32 -> bf16 ----------------
__global__ __launch_bounds__(256) void convert_x(const float* __restrict__ x,
                                                 ushort_t* __restrict__ xb, int n4) {
    int g = blockIdx.x * 256 + threadIdx.x;
    if (g >= n4) return;
    float4 v = ((const float4*)x)[g];
    u16x4 o;
    o[0] = f2bf(v.x); o[1] = f2bf(v.y); o[2] = f2bf(v.z); o[3] = f2bf(v.w);
    ((u16x4*)xb)[g] = o;
}

// ---------------- W [K][N] fp32 -> WT [N][K] bf16 (tiled transpose) ----------------
__global__ __launch_bounds__(256) void transpose_w(const float* __restrict__ W,
                                                   ushort_t* __restrict__ WT, int K, int N) {
    __shared__ ushort_t T[64][72];
    const int n0 = blockIdx.x * 64, k0 = blockIdx.y * 64;
    const int t = threadIdx.x;
    for (int idx = t; idx < 64 * 16; idx += 256) {
        int r = idx >> 4, c4 = (idx & 15) << 2;
        float4 v = *(const float4*)&W[(size_t)(k0 + r) * N + n0 + c4];
        T[r][c4 + 0] = f2bf(v.x); T[r][c4 + 1] = f2bf(v.y);
        T[r][c4 + 2] = f2bf(v.z); T[r][c4 + 3] = f2bf(v.w);
    }
    __syncthreads();
    for (int idx = t; idx < 64 * 16; idx += 256) {
        int n = idx >> 4, kg = (idx & 15) << 2;
        u16x4 o;
        o[0] = T[kg + 0][n]; o[1] = T[kg + 1][n];
        o[2] = T[kg + 2][n]; o[3] = T[kg + 3][n];
        *(u16x4*)&WT[(size_t)(n0 + n) * K + k0 + kg] = o;
    }
}

// ---------------- GEMM C = A[M][K] * Bt[N][K]^T + bias, fused epilogues ----------------
// Double-buffered async staging, one barrier/iter, bank-swizzled LDS.
// MODE 0: fp32 out + bias (final proj)
// MODE 1: RoPE+scale -> Qr bf16 [B][NH][S][HD]
// MODE 4: fused KV. n0<512: RoPE -> Kr [B][NKV][S][HD]; n0>=512: Vt [B][NKV][HD][S]
template <int MODE>
__global__ __launch_bounds__(256) void gemm_bt(const ushort_t* __restrict__ A,
                                               const ushort_t* __restrict__ Bt,
                                               const float* __restrict__ bias,
                                               const float* __restrict__ bias2,
                                               void* __restrict__ out,
                                               void* __restrict__ out2,
                                               int M, int N, int K,
                                               const int* __restrict__ posids) {
    __shared__ __align__(16) ushort_t As[2][128 * 32];
    __shared__ __align__(16) ushort_t Bs[2][128 * 32];
    const int tid = threadIdx.x;
    const int w = tid >> 6, lane = tid & 63, quad = lane >> 4, l16 = lane & 15;
    const int m0 = blockIdx.y * 128, n0 = blockIdx.x * 128;

    f32x4 acc[2][8];
    for (int i = 0; i < 2; i++)
        for (int j = 0; j < 8; j++)
            for (int e = 0; e < 4; e++) acc[i][j][e] = 0.0f;

    // staging: lane -> row-of-16 + swizzled 16B chunk
    const int rr = lane >> 2;
    const int gc8 = (((lane & 3) ^ ((lane >> 3) & 3)) << 3);  // swizzled global chunk (shorts)
    const ushort_t* Ag = A + (size_t)(m0 + w * 32 + rr) * K + gc8;
    const ushort_t* Bg = Bt + (size_t)(n0 + w * 32 + rr) * K + gc8;
    ushort_t* Al0 = &As[0][(w * 32) * 32];
    ushort_t* Bl0 = &Bs[0][(w * 32) * 32];

    auto stage = [&](int bi, int k0) {
        const ushort_t* ag = Ag + k0;
        const ushort_t* bg = Bg + k0;
        ushort_t* la = Al0 + bi * 128 * 32;
        ushort_t* lb = Bl0 + bi * 128 * 32;
        load_lds16(ag, la);
        load_lds16(ag + (size_t)16 * K, la + 512);
        load_lds16(bg, lb);
        load_lds16(bg + (size_t)16 * K, lb + 512);
    };

    const int nk = K >> 5;
    const int rsw = ((l16 >> 1) & 3);  // reader swizzle
    stage(0, 0);
    __syncthreads();

    for (int ki = 0; ki < nk; ki++) {
        const int cur = ki & 1;
        if (ki + 1 < nk) stage(cur ^ 1, (ki + 1) << 5);
        const ushort_t* Ab = As[cur];
        const ushort_t* Bb = Bs[cur];
        bf16x8 af[2];
#pragma unroll
        for (int i = 0; i < 2; i++)
            af[i] = *(const bf16x8*)&Ab[(w * 32 + i * 16 + l16) * 32 + (quad ^ rsw) * 8];
#pragma unroll
        for (int j = 0; j < 8; j++) {
            bf16x8 bf = *(const bf16x8*)&Bb[(j * 16 + l16) * 32 + (quad ^ rsw) * 8];
#pragma unroll
            for (int i = 0; i < 2; i++) acc[i][j] = mfma16(af[i], bf, acc[i][j]);
        }
        __syncthreads();
    }

    // ---- epilogues ----
    if (MODE == 0) {
        float* O = (float*)out;
#pragma unroll
        for (int i = 0; i < 2; i++)
#pragma unroll
            for (int r = 0; r < 4; r++) {
                int row = m0 + w * 32 + i * 16 + quad * 4 + r;
#pragma unroll
                for (int j = 0; j < 8; j++) {
                    int col = n0 + j * 16 + l16;
                    O[(size_t)row * N + col] = acc[i][j][r] + bias[col];
                }
            }
    } else if (MODE == 1) {
        ushort_t* O = (ushort_t*)out;
        const int h = n0 >> 7;
        const float scale = 0.08838834764831845f;
#pragma unroll
        for (int i = 0; i < 2; i++)
#pragma unroll
            for (int r = 0; r < 4; r++) {
                int row = m0 + w * 32 + i * 16 + quad * 4 + r;  // b*SEQ + s
                int b = row >> 11, s = row & (SEQ - 1);
                float pos = (float)posids[row];
                size_t obase = ((size_t)(b * NH + h) * SEQ + s) * HD;
#pragma unroll
                for (int j = 0; j < 4; j++) {
                    int dl = j * 16 + l16;  // 0..63
                    float x1 = acc[i][j][r] + bias[n0 + dl];
                    float x2 = acc[i][j + 4][r] + bias[n0 + dl + 64];
                    float ang = pos * __expf(-0.21586735246819178f * (float)dl);
                    float sn, cs;
                    __sincosf(ang, &sn, &cs);
                    O[obase + dl]      = f2bf((x1 * cs - x2 * sn) * scale);
                    O[obase + dl + 64] = f2bf((x2 * cs + x1 * sn) * scale);
                }
            }
    } else {  // MODE 4 fused KV
        if (n0 < 512) {  // K path with RoPE
            ushort_t* O = (ushort_t*)out;
            const int h = n0 >> 7;
#pragma unroll
            for (int i = 0; i < 2; i++)
#pragma unroll
                for (int r = 0; r < 4; r++) {
                    int row = m0 + w * 32 + i * 16 + quad * 4 + r;
                    int b = row >> 11, s = row & (SEQ - 1);
                    float pos = (float)posids[row];
                    size_t obase = ((size_t)(b * NKV + h) * SEQ + s) * HD;
#pragma unroll
                    for (int j = 0; j < 4; j++) {
                        int dl = j * 16 + l16;
                        float x1 = acc[i][j][r] + bias[n0 + dl];
                        float x2 = acc[i][j + 4][r] + bias[n0 + dl + 64];
                        float ang = pos * __expf(-0.21586735246819178f * (float)dl);
                        float sn, cs;
                        __sincosf(ang, &sn, &cs);
                        O[obase + dl]      = f2bf(x1 * cs - x2 * sn);
                        O[obase + dl + 64] = f2bf(x2 * cs + x1 * sn);
                    }
                }
        } else {  // V path, transposed store
            ushort_t* O = (ushort_t*)out2;
            const int n0v = n0 - 512;
            const int h = n0v >> 7;
#pragma unroll
            for (int i = 0; i < 2; i++)
#pragma unroll
                for (int r = 0; r < 4; r++) {
                    int row = m0 + w * 32 + i * 16 + quad * 4 + r;
                    int b = row >> 11, s = row & (SEQ - 1);
#pragma unroll
                    for (int j = 0; j < 8; j++) {
                        int d = (n0v & 127) + j * 16 + l16;  // 0..127 within head
                        float v = acc[i][j][r] + bias2[n0v + j * 16 + l16];
                        O[((size_t)(b * NKV + h) * HD + d) * SEQ + s] = f2bf(v);
                    }
                }
        }
    }
}

// ---------------- causal GQA flash attention, double-buffered + swizzled ----------------
// Qr [B][NH][S][HD], Kr [B][NKV][S][HD], Vt [B][NKV][HD][S] -> Attn bf16 [B*S][HIDDEN]
// Fixed-reference softmax (m=0): scores bounded |s| <~ 9.4, exp() safe in fp32.
__global__ __launch_bounds__(256) void flash(const ushort_t* __restrict__ Qr,
                                             const ushort_t* __restrict__ Kr,
                                             const ushort_t* __restrict__ Vt,
                                             ushort_t* __restrict__ Attn) {
    // Ks: [buf2][kc4][seg4][16rows][32], Vs: [buf2][kc2][128rows][32], Ps: per-wave 16x72
    __shared__ __align__(16) ushort_t Ksh[2 * 4 * 64 * 32];
    __shared__ __align__(16) ushort_t Vsh[2 * 2 * 128 * 32];
    __shared__ __align__(16) ushort_t Ps[4 * 16 * 72];
    const int tid = threadIdx.x;
    const int w = tid >> 6, lane = tid & 63, quad = lane >> 4, l16 = lane & 15;
    const int qt = (gridDim.x - 1) - blockIdx.x;  // longest blocks first
    const int h = blockIdx.y, b = blockIdx.z;
    const int hkv = h >> 2;
    const int q0 = qt * 64;
    const ushort_t* Kg = Kr + ((size_t)(b * NKV + hkv) * SEQ) * HD;
    const ushort_t* Vg = Vt + ((size_t)(b * NKV + hkv) * HD) * SEQ;

    // staging addresses (swizzled global chunk)
    const int p = lane >> 2;
    const int gc8 = (((lane & 3) ^ ((lane >> 3) & 3)) << 3);
    // K: wave w stages k-chunk kc=w (cols w*32..+31), 4 calls of 16 rows
    const ushort_t* kst = Kg + (size_t)p * HD + w * 32 + gc8;
    // V: wave w stages k-chunk w>>1, row-half (w&1)*64, 4 calls of 16 rows
    const ushort_t* vst = Vg + (size_t)((w & 1) * 64 + p) * SEQ + (w >> 1) * 32 + gc8;
    ushort_t* ksl = Ksh + w * 2048;                             // + buf*8192, + call*512
    ushort_t* vsl = Vsh + (w >> 1) * 4096 + (w & 1) * 2048;     // + buf*8192, + call*512

    auto stage = [&](int bi, int kv0) {
        const ushort_t* gk = kst + (size_t)kv0 * HD;
        ushort_t* lk = ksl + bi * 8192;
        load_lds16(gk, lk);
        load_lds16(gk + (size_t)16 * HD, lk + 512);
        load_lds16(gk + (size_t)32 * HD, lk + 1024);
        load_lds16(gk + (size_t)48 * HD, lk + 1536);
        const ushort_t* gv = vst + kv0;
        ushort_t* lv = vsl + bi * 8192;
        load_lds16(gv, lv);
        load_lds16(gv + (size_t)16 * SEQ, lv + 512);
        load_lds16(gv + (size_t)32 * SEQ, lv + 1024);
        load_lds16(gv + (size_t)48 * SEQ, lv + 1536);
    };

    // Q fragments in registers (A-operand layout, 4 k-chunks of 32)
    bf16x8 aq[4];
    {
        const size_t qrow = ((size_t)(b * NH + h) * SEQ + q0 + w * 16 + l16) * HD;
#pragma unroll
        for (int kc = 0; kc < 4; kc++)
            aq[kc] = *(const bf16x8*)&Qr[qrow + kc * 32 + quad * 8];
    }

    f32x4 o[8];
#pragma unroll
    for (int j = 0; j < 8; j++)
#pragma unroll
        for (int e = 0; e < 4; e++) o[j][e] = 0.0f;
    f32x4 ls;  // row sums via MFMA vs all-ones B
    for (int e = 0; e < 4; e++) ls[e] = 0.0f;
    bf16x8 ones;
#pragma unroll
    for (int e = 0; e < 8; e++) ones[e] = (short)0x3F80;  // bf16 1.0

    ushort_t* Pw = &Ps[w * 16 * 72];
    const int rsw8 = ((l16 >> 1) & 3) << 3;  // reader swizzle (shorts), XOR with quad*8

    stage(0, 0);
    __syncthreads();  // buf0 staged

    for (int kt = 0; kt <= qt; kt++) {
        const int kv0 = kt * 64;
        const int cur = kt & 1;
        if (kt < qt) stage(cur ^ 1, kv0 + 64);  // async prefetch next tile

        const ushort_t* Kb = Ksh + cur * 8192;
        const ushort_t* Vb = Vsh + cur * 8192;

        // QK^T
        f32x4 sa[4];
#pragma unroll
        for (int nt = 0; nt < 4; nt++)
#pragma unroll
            for (int e = 0; e < 4; e++) sa[nt][e] = 0.0f;
#pragma unroll
        for (int kc = 0; kc < 4; kc++) {
#pragma unroll
            for (int nt = 0; nt < 4; nt++) {
                bf16x8 bk = *(const bf16x8*)&Kb[kc * 2048 + nt * 512 + l16 * 32 +
                                                ((quad * 8) ^ rsw8)];
                sa[nt] = mfma16(aq[kc], bk, sa[nt]);
            }
        }

        if (kt == qt) {
#pragma unroll
            for (int nt = 0; nt < 4; nt++)
#pragma unroll
                for (int r = 0; r < 4; r++) {
                    int kvg = kv0 + nt * 16 + l16;
                    int qg = q0 + w * 16 + quad * 4 + r;
                    if (kvg > qg) sa[nt][r] = -1e30f;
                }
        }

        // P = exp(s), bf16-truncate, per-wave LDS round-trip (C-layout -> A-layout)
#pragma unroll
        for (int nt = 0; nt < 4; nt++)
#pragma unroll
            for (int r = 0; r < 4; r++)
                Pw[(quad * 4 + r) * 72 + nt * 16 + l16] = f2bf_trunc(__expf(sa[nt][r]));

        // PV
#pragma unroll
        for (int kc = 0; kc < 2; kc++) {
            bf16x8 ap = *(const bf16x8*)&Pw[l16 * 72 + kc * 32 + quad * 8];
            ls = mfma16(ap, ones, ls);  // row sums
#pragma unroll
            for (int j = 0; j < 8; j++) {
                bf16x8 bv = *(const bf16x8*)&Vb[kc * 4096 + (j * 16 + l16) * 32 +
                                                ((quad * 8) ^ rsw8)];
                o[j] = mfma16(ap, bv, o[j]);
            }
        }
        __syncthreads();  // drains prefetch (had whole compute phase) + guards buffer reuse
    }

#pragma unroll
    for (int r = 0; r < 4; r++) {
        float inv = 1.0f / ls[r];
        int row = b * SEQ + q0 + w * 16 + quad * 4 + r;
        size_t obase = (size_t)row * HIDDEN + h * HD;
#pragma unroll
        for (int j = 0; j < 8; j++) Attn[obase + j * 16 + l16] = f2bf(o[j][r] * inv);
    }
}

extern "C" void kernel_launch(void* const* d_in, const int* in_sizes, int n_in,
                              void* d_out, int out_size, void* d_ws, size_t ws_size,
                              hipStream_t stream) {
    const float* hs = (const float*)d_in[0];
    const int* posids = (const int*)d_in[1];
    const float* Wq = (const float*)d_in[2];
    const float* bq = (const float*)d_in[3];
    const float* Wk = (const float*)d_in[4];
    const float* bk = (const float*)d_in[5];
    const float* Wv = (const float*)d_in[6];
    const float* bv = (const float*)d_in[7];
    const float* Wo = (const float*)d_in[8];
    const float* bo = (const float*)d_in[9];
    float* out = (float*)d_out;

    char* ws = (char*)d_ws;
    size_t off = 0;
    auto alloc = [&](size_t bytes) {
        char* p = ws + off;
        off += (bytes + 255) & ~(size_t)255;
        return p;
    };
    ushort_t* Xb   = (ushort_t*)alloc(4096ull * 2048 * 2);
    ushort_t* WqT  = (ushort_t*)alloc(2048ull * 2048 * 2);
    ushort_t* WkvT = (ushort_t*)alloc(1024ull * 2048 * 2);  // rows 0..511 = Wk^T, 512..1023 = Wv^T
    ushort_t* WoT  = (ushort_t*)alloc(2048ull * 2048 * 2);
    ushort_t* Qr   = (ushort_t*)alloc((size_t)BATCH * NH * SEQ * HD * 2);
    ushort_t* Kr   = (ushort_t*)alloc((size_t)BATCH * NKV * SEQ * HD * 2);
    ushort_t* Vtr  = (ushort_t*)alloc((size_t)BATCH * NKV * HD * SEQ * 2);
    ushort_t* Attn = (ushort_t*)alloc(4096ull * 2048 * 2);

    convert_x<<<4096 * 2048 / 4 / 256, 256, 0, stream>>>(hs, Xb, 4096 * 2048 / 4);
    transpose_w<<<dim3(2048 / 64, 2048 / 64), 256, 0, stream>>>(Wq, WqT, 2048, 2048);
    transpose_w<<<dim3(512 / 64, 2048 / 64), 256, 0, stream>>>(Wk, WkvT, 2048, 512);
    transpose_w<<<dim3(512 / 64, 2048 / 64), 256, 0, stream>>>(Wv, WkvT + 512ull * 2048, 2048, 512);
    transpose_w<<<dim3(2048 / 64, 2048 / 64), 256, 0, stream>>>(Wo, WoT, 2048, 2048);

    gemm_bt<1><<<dim3(16, 32), 256, 0, stream>>>(Xb, WqT, bq, nullptr, Qr, nullptr,
                                                 4096, 2048, 2048, posids);
    gemm_bt<4><<<dim3(8, 32), 256, 0, stream>>>(Xb, WkvT, bk, bv, Kr, Vtr,
                                                4096, 1024, 2048, posids);

    flash<<<dim3(SEQ / 64, NH, BATCH), 256, 0, stream>>>(Qr, Kr, Vtr, Attn);

    gemm_bt<0><<<dim3(16, 32), 256, 0, stream>>>(Attn, WoT, bo, nullptr, out, nullptr,
                                                 4096, 2048, 2048, nullptr);
}

// Round 6
// 361.883 us; speedup vs baseline: 2.0727x; 1.0470x over previous
//
#include <hip/hip_runtime.h>
#include <cmath>

#define HIDDEN 2048
#define NH 16
#define NKV 4
#define HD 128
#define SEQ 2048
#define BATCH 2

typedef unsigned short ushort_t;
typedef short bf16x8 __attribute__((ext_vector_type(8)));
typedef float f32x4 __attribute__((ext_vector_type(4)));
typedef ushort_t u16x4 __attribute__((ext_vector_type(4)));

__device__ __forceinline__ ushort_t f2bf(float f) {
    union { float f; unsigned int u; } v; v.f = f;
    unsigned int r = v.u + 0x7fffu + ((v.u >> 16) & 1u);
    return (ushort_t)(r >> 16);
}
__device__ __forceinline__ ushort_t f2bf_trunc(float f) {
    union { float f; unsigned int u; } v; v.f = f;
    return (ushort_t)(v.u >> 16);
}

__device__ __forceinline__ f32x4 mfma16(bf16x8 a, bf16x8 b, f32x4 c) {
    return __builtin_amdgcn_mfma_f32_16x16x32_bf16(a, b, c, 0, 0, 0);
}

// async global -> LDS, 16B per lane. LDS dst is wave-uniform base + lane*16.
__device__ __forceinline__ void load_lds16(const void* g, void* l) {
    __builtin_amdgcn_global_load_lds((const __attribute__((address_space(1))) unsigned int*)g,
                                     (__attribute__((address_space(3))) unsigned int*)l,
                                     16, 0, 0);
}

// Bank-swizzle scheme for [rows x 32shorts] tiles staged via global_load_lds:
// 16B-chunk c of row p lives at chunk-position cp = c ^ ((p>>1)&3).
// Staging lane l (p=l>>2, cp=l&3) therefore loads global chunk (l&3)^((l>>3)&3).
// Reader of chunk q at row r uses position q^((r>>1)&3). -> 2-way bank access (free).

// ---------------- elementwise fp32 -> bf16 ----------------
__global__ __launch_bounds__(256) void convert_x(const float* __restrict__ x,
                                                 ushort_t* __restrict__ xb, int n4) {
    int g = blockIdx.x * 256 + threadIdx.x;
    if (g >= n4) return;
    float4 v = ((const float4*)x)[g];
    u16x4 o;
    o[0] = f2bf(v.x); o[1] = f2bf(v.y); o[2] = f2bf(v.z); o[3] = f2bf(v.w);
    ((u16x4*)xb)[g] = o;
}

// ---------------- W [K][N] fp32 -> WT [N][K] bf16 (tiled transpose) ----------------
__global__ __launch_bounds__(256) void transpose_w(const float* __restrict__ W,
                                                   ushort_t* __restrict__ WT, int K, int N) {
    __shared__ ushort_t T[64][72];
    const int n0 = blockIdx.x * 64, k0 = blockIdx.y * 64;
    const int t = threadIdx.x;
    for (int idx = t; idx < 64 * 16; idx += 256) {
        int r = idx >> 4, c4 = (idx & 15) << 2;
        float4 v = *(const float4*)&W[(size_t)(k0 + r) * N + n0 + c4];
        T[r][c4 + 0] = f2bf(v.x); T[r][c4 + 1] = f2bf(v.y);
        T[r][c4 + 2] = f2bf(v.z); T[r][c4 + 3] = f2bf(v.w);
    }
    __syncthreads();
    for (int idx = t; idx < 64 * 16; idx += 256) {
        int n = idx >> 4, kg = (idx & 15) << 2;
        u16x4 o;
        o[0] = T[kg + 0][n]; o[1] = T[kg + 1][n];
        o[2] = T[kg + 2][n]; o[3] = T[kg + 3][n];
        *(u16x4*)&WT[(size_t)(n0 + n) * K + k0 + kg] = o;
    }
}

// ---------------- GEMM C = A[M][K] * Bt[N][K]^T + bias, fused epilogues ----------------
// Double-buffered async staging, one barrier/iter, bank-swizzled LDS.
// MODE 0: fp32 out + bias (final proj)
// MODE 1: RoPE+scale -> Qr bf16 [B][NH][S][HD]
// MODE 4: fused KV. n0<512: RoPE -> Kr [B][NKV][S][HD]; n0>=512: Vt [B][NKV][HD][S]
template <int MODE>
__global__ __launch_bounds__(256) void gemm_bt(const ushort_t* __restrict__ A,
                                               const ushort_t* __restrict__ Bt,
                                               const float* __restrict__ bias,
                                               const float* __restrict__ bias2,
                                               void* __restrict__ out,
                                               void* __restrict__ out2,
                                               int M, int N, int K,
                                               const int* __restrict__ posids) {
    __shared__ __align__(16) ushort_t As[2][128 * 32];
    __shared__ __align__(16) ushort_t Bs[2][128 * 32];
    const int tid = threadIdx.x;
    const int w = tid >> 6, lane = tid & 63, quad = lane >> 4, l16 = lane & 15;
    const int m0 = blockIdx.y * 128, n0 = blockIdx.x * 128;

    f32x4 acc[2][8];
    for (int i = 0; i < 2; i++)
        for (int j = 0; j < 8; j++)
            for (int e = 0; e < 4; e++) acc[i][j][e] = 0.0f;

    // staging: lane -> row-of-16 + swizzled 16B chunk
    const int rr = lane >> 2;
    const int gc8 = (((lane & 3) ^ ((lane >> 3) & 3)) << 3);  // swizzled global chunk (shorts)
    const ushort_t* Ag = A + (size_t)(m0 + w * 32 + rr) * K + gc8;
    const ushort_t* Bg = Bt + (size_t)(n0 + w * 32 + rr) * K + gc8;
    ushort_t* Al0 = &As[0][(w * 32) * 32];
    ushort_t* Bl0 = &Bs[0][(w * 32) * 32];

    auto stage = [&](int bi, int k0) {
        const ushort_t* ag = Ag + k0;
        const ushort_t* bg = Bg + k0;
        ushort_t* la = Al0 + bi * 128 * 32;
        ushort_t* lb = Bl0 + bi * 128 * 32;
        load_lds16(ag, la);
        load_lds16(ag + (size_t)16 * K, la + 512);
        load_lds16(bg, lb);
        load_lds16(bg + (size_t)16 * K, lb + 512);
    };

    const int nk = K >> 5;
    const int rsw = ((l16 >> 1) & 3);  // reader swizzle
    stage(0, 0);
    __syncthreads();

    for (int ki = 0; ki < nk; ki++) {
        const int cur = ki & 1;
        if (ki + 1 < nk) stage(cur ^ 1, (ki + 1) << 5);
        const ushort_t* Ab = As[cur];
        const ushort_t* Bb = Bs[cur];
        bf16x8 af[2];
#pragma unroll
        for (int i = 0; i < 2; i++)
            af[i] = *(const bf16x8*)&Ab[(w * 32 + i * 16 + l16) * 32 + (quad ^ rsw) * 8];
#pragma unroll
        for (int j = 0; j < 8; j++) {
            bf16x8 bf = *(const bf16x8*)&Bb[(j * 16 + l16) * 32 + (quad ^ rsw) * 8];
#pragma unroll
            for (int i = 0; i < 2; i++) acc[i][j] = mfma16(af[i], bf, acc[i][j]);
        }
        __syncthreads();
    }

    // ---- epilogues ----
    if (MODE == 0) {
        float* O = (float*)out;
#pragma unroll
        for (int i = 0; i < 2; i++)
#pragma unroll
            for (int r = 0; r < 4; r++) {
                int row = m0 + w * 32 + i * 16 + quad * 4 + r;
#pragma unroll
                for (int j = 0; j < 8; j++) {
                    int col = n0 + j * 16 + l16;
                    O[(size_t)row * N + col] = acc[i][j][r] + bias[col];
                }
            }
    } else if (MODE == 1) {
        ushort_t* O = (ushort_t*)out;
        const int h = n0 >> 7;
        const float scale = 0.08838834764831845f;
#pragma unroll
        for (int i = 0; i < 2; i++)
#pragma unroll
            for (int r = 0; r < 4; r++) {
                int row = m0 + w * 32 + i * 16 + quad * 4 + r;  // b*SEQ + s
                int b = row >> 11, s = row & (SEQ - 1);
                float pos = (float)posids[row];
                size_t obase = ((size_t)(b * NH + h) * SEQ + s) * HD;
#pragma unroll
                for (int j = 0; j < 4; j++) {
                    int dl = j * 16 + l16;  // 0..63
                    float x1 = acc[i][j][r] + bias[n0 + dl];
                    float x2 = acc[i][j + 4][r] + bias[n0 + dl + 64];
                    float ang = pos * __expf(-0.21586735246819178f * (float)dl);
                    float sn, cs;
                    __sincosf(ang, &sn, &cs);
                    O[obase + dl]      = f2bf((x1 * cs - x2 * sn) * scale);
                    O[obase + dl + 64] = f2bf((x2 * cs + x1 * sn) * scale);
                }
            }
    } else {  // MODE 4 fused KV
        if (n0 < 512) {  // K path with RoPE
            ushort_t* O = (ushort_t*)out;
            const int h = n0 >> 7;
#pragma unroll
            for (int i = 0; i < 2; i++)
#pragma unroll
                for (int r = 0; r < 4; r++) {
                    int row = m0 + w * 32 + i * 16 + quad * 4 + r;
                    int b = row >> 11, s = row & (SEQ - 1);
                    float pos = (float)posids[row];
                    size_t obase = ((size_t)(b * NKV + h) * SEQ + s) * HD;
#pragma unroll
                    for (int j = 0; j < 4; j++) {
                        int dl = j * 16 + l16;
                        float x1 = acc[i][j][r] + bias[n0 + dl];
                        float x2 = acc[i][j + 4][r] + bias[n0 + dl + 64];
                        float ang = pos * __expf(-0.21586735246819178f * (float)dl);
                        float sn, cs;
                        __sincosf(ang, &sn, &cs);
                        O[obase + dl]      = f2bf(x1 * cs - x2 * sn);
                        O[obase + dl + 64] = f2bf(x2 * cs + x1 * sn);
                    }
                }
        } else {  // V path, transposed store
            ushort_t* O = (ushort_t*)out2;
            const int n0v = n0 - 512;
            const int h = n0v >> 7;
#pragma unroll
            for (int i = 0; i < 2; i++)
#pragma unroll
                for (int r = 0; r < 4; r++) {
                    int row = m0 + w * 32 + i * 16 + quad * 4 + r;
                    int b = row >> 11, s = row & (SEQ - 1);
#pragma unroll
                    for (int j = 0; j < 8; j++) {
                        int d = (n0v & 127) + j * 16 + l16;  // 0..127 within head
                        float v = acc[i][j][r] + bias2[n0v + j * 16 + l16];
                        O[((size_t)(b * NKV + h) * HD + d) * SEQ + s] = f2bf(v);
                    }
                }
        }
    }
}

// ---------------- causal GQA flash attention, Q128 double-buffered + swizzled ----------------
// Qr [B][NH][S][HD], Kr [B][NKV][S][HD], Vt [B][NKV][HD][S] -> Attn bf16 [B*S][HIDDEN]
// 128 q-rows per block (2 subtiles of 64/wave-row-group); kv-tile = 64.
// Fixed-reference softmax (m=0): scores bounded |s| <~ 9.4, exp() safe in fp32.
__global__ __launch_bounds__(256) void flash(const ushort_t* __restrict__ Qr,
                                             const ushort_t* __restrict__ Kr,
                                             const ushort_t* __restrict__ Vt,
                                             ushort_t* __restrict__ Attn) {
    __shared__ __align__(16) ushort_t Ksh[2 * 4 * 64 * 32];   // 32 KB
    __shared__ __align__(16) ushort_t Vsh[2 * 2 * 128 * 32];  // 32 KB
    __shared__ __align__(16) ushort_t Ps[4 * 16 * 72];        // 9 KB, per-wave, shared by subtiles
    const int tid = threadIdx.x;
    const int w = tid >> 6, lane = tid & 63, quad = lane >> 4, l16 = lane & 15;
    const int x = blockIdx.x, h = blockIdx.y, b = blockIdx.z;
    // pair-balance: co-resident blocks L and L+256 differ only in b -> qt sums constant
    const int qt = b ? x : (gridDim.x - 1 - x);
    const int q0 = qt * 128;
    const int nkt = 2 * qt + 2;
    const int hkv = h >> 2;
    const ushort_t* Kg = Kr + ((size_t)(b * NKV + hkv) * SEQ) * HD;
    const ushort_t* Vg = Vt + ((size_t)(b * NKV + hkv) * HD) * SEQ;

    // staging addresses (swizzled global chunk)
    const int p = lane >> 2;
    const int gc8 = (((lane & 3) ^ ((lane >> 3) & 3)) << 3);
    const ushort_t* kst = Kg + (size_t)p * HD + w * 32 + gc8;
    const ushort_t* vst = Vg + (size_t)((w & 1) * 64 + p) * SEQ + (w >> 1) * 32 + gc8;
    ushort_t* ksl = Ksh + w * 2048;
    ushort_t* vsl = Vsh + (w >> 1) * 4096 + (w & 1) * 2048;

    auto stage = [&](int bi, int kv0) {
        const ushort_t* gk = kst + (size_t)kv0 * HD;
        ushort_t* lk = ksl + bi * 8192;
        load_lds16(gk, lk);
        load_lds16(gk + (size_t)16 * HD, lk + 512);
        load_lds16(gk + (size_t)32 * HD, lk + 1024);
        load_lds16(gk + (size_t)48 * HD, lk + 1536);
        const ushort_t* gv = vst + kv0;
        ushort_t* lv = vsl + bi * 8192;
        load_lds16(gv, lv);
        load_lds16(gv + (size_t)16 * SEQ, lv + 512);
        load_lds16(gv + (size_t)32 * SEQ, lv + 1024);
        load_lds16(gv + (size_t)48 * SEQ, lv + 1536);
    };

    // Q fragments in registers: 2 subtiles x 4 k-chunks
    bf16x8 aq[2][4];
#pragma unroll
    for (int st = 0; st < 2; st++) {
        const size_t qrow = ((size_t)(b * NH + h) * SEQ + q0 + st * 64 + w * 16 + l16) * HD;
#pragma unroll
        for (int kc = 0; kc < 4; kc++)
            aq[st][kc] = *(const bf16x8*)&Qr[qrow + kc * 32 + quad * 8];
    }

    f32x4 o[2][8];
#pragma unroll
    for (int st = 0; st < 2; st++)
#pragma unroll
        for (int j = 0; j < 8; j++)
#pragma unroll
            for (int e = 0; e < 4; e++) o[st][j][e] = 0.0f;
    f32x4 ls2[2];
#pragma unroll
    for (int st = 0; st < 2; st++)
        for (int e = 0; e < 4; e++) ls2[st][e] = 0.0f;
    bf16x8 ones;
#pragma unroll
    for (int e = 0; e < 8; e++) ones[e] = (short)0x3F80;  // bf16 1.0

    ushort_t* Pw = &Ps[w * 16 * 72];
    const int rsw8 = ((l16 >> 1) & 3) << 3;  // reader swizzle (shorts), XOR with quad*8

    stage(0, 0);
    __syncthreads();  // buf0 staged

    for (int kt = 0; kt < nkt; kt++) {
        const int kv0 = kt * 64;
        const int cur = kt & 1;
        if (kt + 1 < nkt) stage(cur ^ 1, kv0 + 64);  // async prefetch next tile

        const ushort_t* Kb = Ksh + cur * 8192;
        const ushort_t* Vb = Vsh + cur * 8192;

#pragma unroll
        for (int st = 0; st < 2; st++) {
            // subtile 0 is fully masked on the last (odd-diagonal) tile
            if (st == 0 && kt == 2 * qt + 1) continue;

            // QK^T
            f32x4 sa[4];
#pragma unroll
            for (int nt = 0; nt < 4; nt++)
#pragma unroll
                for (int e = 0; e < 4; e++) sa[nt][e] = 0.0f;
#pragma unroll
            for (int kc = 0; kc < 4; kc++) {
#pragma unroll
                for (int nt = 0; nt < 4; nt++) {
                    bf16x8 bk = *(const bf16x8*)&Kb[kc * 2048 + nt * 512 + l16 * 32 +
                                                    ((quad * 8) ^ rsw8)];
                    sa[nt] = mfma16(aq[st][kc], bk, sa[nt]);
                }
            }

            // causal mask on the diagonal tile of this subtile
            if ((kt >> 1) == qt && (kt & 1) == st) {
#pragma unroll
                for (int nt = 0; nt < 4; nt++)
#pragma unroll
                    for (int r = 0; r < 4; r++) {
                        int kvg = kv0 + nt * 16 + l16;
                        int qg = q0 + st * 64 + w * 16 + quad * 4 + r;
                        if (kvg > qg) sa[nt][r] = -1e30f;
                    }
            }

            // P = exp(s), bf16-truncate, per-wave LDS round-trip (C-layout -> A-layout)
#pragma unroll
            for (int nt = 0; nt < 4; nt++)
#pragma unroll
                for (int r = 0; r < 4; r++)
                    Pw[(quad * 4 + r) * 72 + nt * 16 + l16] = f2bf_trunc(__expf(sa[nt][r]));

            // PV
#pragma unroll
            for (int kc = 0; kc < 2; kc++) {
                bf16x8 ap = *(const bf16x8*)&Pw[l16 * 72 + kc * 32 + quad * 8];
                ls2[st] = mfma16(ap, ones, ls2[st]);  // row sums
#pragma unroll
                for (int j = 0; j < 8; j++) {
                    bf16x8 bv = *(const bf16x8*)&Vb[kc * 4096 + (j * 16 + l16) * 32 +
                                                    ((quad * 8) ^ rsw8)];
                    o[st][j] = mfma16(ap, bv, o[st][j]);
                }
            }
        }
        __syncthreads();  // drains prefetch + guards buffer reuse
    }

#pragma unroll
    for (int st = 0; st < 2; st++)
#pragma unroll
        for (int r = 0; r < 4; r++) {
            float inv = 1.0f / ls2[st][r];
            int row = b * SEQ + q0 + st * 64 + w * 16 + quad * 4 + r;
            size_t obase = (size_t)row * HIDDEN + h * HD;
#pragma unroll
            for (int j = 0; j < 8; j++) Attn[obase + j * 16 + l16] = f2bf(o[st][j][r] * inv);
        }
}

extern "C" void kernel_launch(void* const* d_in, const int* in_sizes, int n_in,
                              void* d_out, int out_size, void* d_ws, size_t ws_size,
                              hipStream_t stream) {
    const float* hs = (const float*)d_in[0];
    const int* posids = (const int*)d_in[1];
    const float* Wq = (const float*)d_in[2];
    const float* bq = (const float*)d_in[3];
    const float* Wk = (const float*)d_in[4];
    const float* bk = (const float*)d_in[5];
    const float* Wv = (const float*)d_in[6];
    const float* bv = (const float*)d_in[7];
    const float* Wo = (const float*)d_in[8];
    const float* bo = (const float*)d_in[9];
    float* out = (float*)d_out;

    char* ws = (char*)d_ws;
    size_t off = 0;
    auto alloc = [&](size_t bytes) {
        char* p = ws + off;
        off += (bytes + 255) & ~(size_t)255;
        return p;
    };
    ushort_t* Xb   = (ushort_t*)alloc(4096ull * 2048 * 2);
    ushort_t* WqT  = (ushort_t*)alloc(2048ull * 2048 * 2);
    ushort_t* WkvT = (ushort_t*)alloc(1024ull * 2048 * 2);  // rows 0..511 = Wk^T, 512..1023 = Wv^T
    ushort_t* WoT  = (ushort_t*)alloc(2048ull * 2048 * 2);
    ushort_t* Qr   = (ushort_t*)alloc((size_t)BATCH * NH * SEQ * HD * 2);
    ushort_t* Kr   = (ushort_t*)alloc((size_t)BATCH * NKV * SEQ * HD * 2);
    ushort_t* Vtr  = (ushort_t*)alloc((size_t)BATCH * NKV * HD * SEQ * 2);
    ushort_t* Attn = (ushort_t*)alloc(4096ull * 2048 * 2);

    convert_x<<<4096 * 2048 / 4 / 256, 256, 0, stream>>>(hs, Xb, 4096 * 2048 / 4);
    transpose_w<<<dim3(2048 / 64, 2048 / 64), 256, 0, stream>>>(Wq, WqT, 2048, 2048);
    transpose_w<<<dim3(512 / 64, 2048 / 64), 256, 0, stream>>>(Wk, WkvT, 2048, 512);
    transpose_w<<<dim3(512 / 64, 2048 / 64), 256, 0, stream>>>(Wv, WkvT + 512ull * 2048, 2048, 512);
    transpose_w<<<dim3(2048 / 64, 2048 / 64), 256, 0, stream>>>(Wo, WoT, 2048, 2048);

    gemm_bt<1><<<dim3(16, 32), 256, 0, stream>>>(Xb, WqT, bq, nullptr, Qr, nullptr,
                                                 4096, 2048, 2048, posids);
    gemm_bt<4><<<dim3(8, 32), 256, 0, stream>>>(Xb, WkvT, bk, bv, Kr, Vtr,
                                                4096, 1024, 2048, posids);

    flash<<<dim3(SEQ / 128, NH, BATCH), 256, 0, stream>>>(Qr, Kr, Vtr, Attn);

    gemm_bt<0><<<dim3(16, 32), 256, 0, stream>>>(Attn, WoT, bo, nullptr, out, nullptr,
                                                 4096, 2048, 2048, nullptr);
}

// Round 7
// 348.169 us; speedup vs baseline: 2.1543x; 1.0394x over previous
//
#include <hip/hip_runtime.h>
#include <cmath>

#define HIDDEN 2048
#define NH 16
#define NKV 4
#define HD 128
#define SEQ 2048
#define BATCH 2

typedef unsigned short ushort_t;
typedef short bf16x8 __attribute__((ext_vector_type(8)));
typedef float f32x4 __attribute__((ext_vector_type(4)));
typedef ushort_t u16x4 __attribute__((ext_vector_type(4)));

__device__ __forceinline__ ushort_t f2bf(float f) {
    union { float f; unsigned int u; } v; v.f = f;
    unsigned int r = v.u + 0x7fffu + ((v.u >> 16) & 1u);
    return (ushort_t)(r >> 16);
}
__device__ __forceinline__ ushort_t f2bf_trunc(float f) {
    union { float f; unsigned int u; } v; v.f = f;
    return (ushort_t)(v.u >> 16);
}

__device__ __forceinline__ f32x4 mfma16(bf16x8 a, bf16x8 b, f32x4 c) {
    return __builtin_amdgcn_mfma_f32_16x16x32_bf16(a, b, c, 0, 0, 0);
}

// async global -> LDS, 16B per lane. LDS dst is wave-uniform base + lane*16.
__device__ __forceinline__ void load_lds16(const void* g, void* l) {
    __builtin_amdgcn_global_load_lds((const __attribute__((address_space(1))) unsigned int*)g,
                                     (__attribute__((address_space(3))) unsigned int*)l,
                                     16, 0, 0);
}

// Bank-swizzle scheme for [rows x 32shorts] tiles staged via global_load_lds:
// 16B-chunk c of row p lives at chunk-position cp = c ^ ((p>>1)&3).
// Staging lane l (p=l>>2, cp=l&3) loads global chunk (l&3)^((l>>3)&3).
// Reader of chunk q at row r uses position q^((r>>1)&3). -> 2-way bank access (free).

// ---------------- elementwise fp32 -> bf16 ----------------
__global__ __launch_bounds__(256) void convert_x(const float* __restrict__ x,
                                                 ushort_t* __restrict__ xb, int n4) {
    int g = blockIdx.x * 256 + threadIdx.x;
    if (g >= n4) return;
    float4 v = ((const float4*)x)[g];
    u16x4 o;
    o[0] = f2bf(v.x); o[1] = f2bf(v.y); o[2] = f2bf(v.z); o[3] = f2bf(v.w);
    ((u16x4*)xb)[g] = o;
}

// ---------------- all weights: W [K][N] fp32 -> WT [N][K] bf16, one launch ----------------
// z=0: Wq -> WqkvT rows 0..2047 | z=1: Wk -> rows 2048..2559 | z=2: Wv -> rows 2560..3071
// z=3: Wo -> WoT
__global__ __launch_bounds__(256) void transpose_all(const float* __restrict__ Wq,
                                                     const float* __restrict__ Wk,
                                                     const float* __restrict__ Wv,
                                                     const float* __restrict__ Wo,
                                                     ushort_t* __restrict__ WqkvT,
                                                     ushort_t* __restrict__ WoT) {
    const int z = blockIdx.z;
    const float* W;
    ushort_t* WT;
    int N;
    if (z == 0)      { W = Wq; WT = WqkvT;                        N = 2048; }
    else if (z == 1) { W = Wk; WT = WqkvT + 2048ull * 2048;       N = 512;  }
    else if (z == 2) { W = Wv; WT = WqkvT + 2560ull * 2048;       N = 512;  }
    else             { W = Wo; WT = WoT;                          N = 2048; }
    const int K = 2048;
    const int n0 = blockIdx.x * 64, k0 = blockIdx.y * 64;
    if (n0 >= N) return;
    __shared__ ushort_t T[64][72];
    const int t = threadIdx.x;
    for (int idx = t; idx < 64 * 16; idx += 256) {
        int r = idx >> 4, c4 = (idx & 15) << 2;
        float4 v = *(const float4*)&W[(size_t)(k0 + r) * N + n0 + c4];
        T[r][c4 + 0] = f2bf(v.x); T[r][c4 + 1] = f2bf(v.y);
        T[r][c4 + 2] = f2bf(v.z); T[r][c4 + 3] = f2bf(v.w);
    }
    __syncthreads();
    for (int idx = t; idx < 64 * 16; idx += 256) {
        int n = idx >> 4, kg = (idx & 15) << 2;
        u16x4 o;
        o[0] = T[kg + 0][n]; o[1] = T[kg + 1][n];
        o[2] = T[kg + 2][n]; o[3] = T[kg + 3][n];
        *(u16x4*)&WT[(size_t)(n0 + n) * K + k0 + kg] = o;
    }
}

// ---------------- GEMM C = A[M][K] * Bt[N][K]^T + bias, fused epilogues ----------------
// Double-buffered async staging, one barrier per BK-step, bank-swizzled LDS.
// MODE 0: fp32 out + bias (final proj), BK=64.
// MODE 2: fused QKV (N=3072): n0<2048 -> RoPE+scale Qr [B][NH][S][HD];
//         2048<=n0<2560 -> RoPE Kr [B][NKV][S][HD]; n0>=2560 -> Vt [B][NKV][HD][S]. BK=32.
template <int MODE, int BK>
__global__ __launch_bounds__(256) void gemm_bt(const ushort_t* __restrict__ A,
                                               const ushort_t* __restrict__ Bt,
                                               const float* __restrict__ bias,
                                               const float* __restrict__ bias2,
                                               const float* __restrict__ bias3,
                                               void* __restrict__ out,
                                               void* __restrict__ out2,
                                               void* __restrict__ out3,
                                               int M, int N, int K,
                                               const int* __restrict__ posids) {
    constexpr int CH = BK / 32;  // 32-wide k-chunks per step
    __shared__ __align__(16) ushort_t As[2 * CH * 4096];
    __shared__ __align__(16) ushort_t Bs[2 * CH * 4096];
    const int tid = threadIdx.x;
    const int w = tid >> 6, lane = tid & 63, quad = lane >> 4, l16 = lane & 15;
    const int m0 = blockIdx.y * 128, n0 = blockIdx.x * 128;

    f32x4 acc[2][8];
    for (int i = 0; i < 2; i++)
        for (int j = 0; j < 8; j++)
            for (int e = 0; e < 4; e++) acc[i][j][e] = 0.0f;

    // staging: lane -> row-of-16 + swizzled 16B chunk
    const int rr = lane >> 2;
    const int gc8 = (((lane & 3) ^ ((lane >> 3) & 3)) << 3);
    const ushort_t* Ag = A + (size_t)(m0 + w * 32 + rr) * K + gc8;
    const ushort_t* Bg = Bt + (size_t)(n0 + w * 32 + rr) * K + gc8;
    ushort_t* Asw = As + w * 1024;  // wave's 32-row slice inside a chunk
    ushort_t* Bsw = Bs + w * 1024;

    auto stage = [&](int bi, int k0) {
#pragma unroll
        for (int kc = 0; kc < CH; kc++) {
            const ushort_t* ag = Ag + k0 + kc * 32;
            const ushort_t* bg = Bg + k0 + kc * 32;
            ushort_t* la = Asw + (bi * CH + kc) * 4096;
            ushort_t* lb = Bsw + (bi * CH + kc) * 4096;
            load_lds16(ag, la);
            load_lds16(ag + (size_t)16 * K, la + 512);
            load_lds16(bg, lb);
            load_lds16(bg + (size_t)16 * K, lb + 512);
        }
    };

    const int nk = K / BK;
    const int rsw = ((l16 >> 1) & 3);  // reader swizzle
    stage(0, 0);
    __syncthreads();

    for (int ki = 0; ki < nk; ki++) {
        const int cur = ki & 1;
        if (ki + 1 < nk) stage(cur ^ 1, (ki + 1) * BK);
#pragma unroll
        for (int kc = 0; kc < CH; kc++) {
            const ushort_t* Ab = &As[(cur * CH + kc) * 4096];
            const ushort_t* Bb = &Bs[(cur * CH + kc) * 4096];
            bf16x8 af[2];
#pragma unroll
            for (int i = 0; i < 2; i++)
                af[i] = *(const bf16x8*)&Ab[(w * 32 + i * 16 + l16) * 32 + (quad ^ rsw) * 8];
#pragma unroll
            for (int j = 0; j < 8; j++) {
                bf16x8 bf = *(const bf16x8*)&Bb[(j * 16 + l16) * 32 + (quad ^ rsw) * 8];
#pragma unroll
                for (int i = 0; i < 2; i++) acc[i][j] = mfma16(af[i], bf, acc[i][j]);
            }
        }
        __syncthreads();
    }

    // ---- epilogues ----
    if (MODE == 0) {
        float* O = (float*)out;
#pragma unroll
        for (int i = 0; i < 2; i++)
#pragma unroll
            for (int r = 0; r < 4; r++) {
                int row = m0 + w * 32 + i * 16 + quad * 4 + r;
#pragma unroll
                for (int j = 0; j < 8; j++) {
                    int col = n0 + j * 16 + l16;
                    O[(size_t)row * N + col] = acc[i][j][r] + bias[col];
                }
            }
    } else {  // MODE 2: fused QKV
        if (n0 < 2048) {  // Q path: RoPE + scale
            ushort_t* O = (ushort_t*)out;
            const int h = n0 >> 7;
            const float scale = 0.08838834764831845f;
#pragma unroll
            for (int i = 0; i < 2; i++)
#pragma unroll
                for (int r = 0; r < 4; r++) {
                    int row = m0 + w * 32 + i * 16 + quad * 4 + r;  // b*SEQ + s
                    int b = row >> 11, s = row & (SEQ - 1);
                    float pos = (float)posids[row];
                    size_t obase = ((size_t)(b * NH + h) * SEQ + s) * HD;
#pragma unroll
                    for (int j = 0; j < 4; j++) {
                        int dl = j * 16 + l16;  // 0..63
                        float x1 = acc[i][j][r] + bias[n0 + dl];
                        float x2 = acc[i][j + 4][r] + bias[n0 + dl + 64];
                        float ang = pos * __expf(-0.21586735246819178f * (float)dl);
                        float sn, cs;
                        __sincosf(ang, &sn, &cs);
                        O[obase + dl]      = f2bf((x1 * cs - x2 * sn) * scale);
                        O[obase + dl + 64] = f2bf((x2 * cs + x1 * sn) * scale);
                    }
                }
        } else if (n0 < 2560) {  // K path: RoPE
            ushort_t* O = (ushort_t*)out2;
            const int n0k = n0 - 2048;
            const int h = n0k >> 7;
#pragma unroll
            for (int i = 0; i < 2; i++)
#pragma unroll
                for (int r = 0; r < 4; r++) {
                    int row = m0 + w * 32 + i * 16 + quad * 4 + r;
                    int b = row >> 11, s = row & (SEQ - 1);
                    float pos = (float)posids[row];
                    size_t obase = ((size_t)(b * NKV + h) * SEQ + s) * HD;
#pragma unroll
                    for (int j = 0; j < 4; j++) {
                        int dl = j * 16 + l16;
                        float x1 = acc[i][j][r] + bias2[n0k + dl];
                        float x2 = acc[i][j + 4][r] + bias2[n0k + dl + 64];
                        float ang = pos * __expf(-0.21586735246819178f * (float)dl);
                        float sn, cs;
                        __sincosf(ang, &sn, &cs);
                        O[obase + dl]      = f2bf(x1 * cs - x2 * sn);
                        O[obase + dl + 64] = f2bf(x2 * cs + x1 * sn);
                    }
                }
        } else {  // V path: transposed store
            ushort_t* O = (ushort_t*)out3;
            const int n0v = n0 - 2560;
            const int h = n0v >> 7;
#pragma unroll
            for (int i = 0; i < 2; i++)
#pragma unroll
                for (int r = 0; r < 4; r++) {
                    int row = m0 + w * 32 + i * 16 + quad * 4 + r;
                    int b = row >> 11, s = row & (SEQ - 1);
#pragma unroll
                    for (int j = 0; j < 8; j++) {
                        int d = j * 16 + l16;  // head dim 0..127 (tile==head width)
                        float v = acc[i][j][r] + bias3[n0v + d];
                        O[((size_t)(b * NKV + h) * HD + d) * SEQ + s] = f2bf(v);
                    }
                }
        }
    }
}

// ---------------- causal GQA flash attention, Q128 double-buffered + swizzled ----------------
// Qr [B][NH][S][HD], Kr [B][NKV][S][HD], Vt [B][NKV][HD][S] -> Attn bf16 [B*S][HIDDEN]
// 128 q-rows per block (2 subtiles of 64); kv-tile = 64.
// Fixed-reference softmax (m=0): scores bounded |s| <~ 9.4, exp() safe in fp32.
__global__ __launch_bounds__(256) void flash(const ushort_t* __restrict__ Qr,
                                             const ushort_t* __restrict__ Kr,
                                             const ushort_t* __restrict__ Vt,
                                             ushort_t* __restrict__ Attn) {
    __shared__ __align__(16) ushort_t Ksh[2 * 4 * 64 * 32];   // 32 KB
    __shared__ __align__(16) ushort_t Vsh[2 * 2 * 128 * 32];  // 32 KB
    __shared__ __align__(16) ushort_t Ps[4 * 16 * 72];        // 9 KB, per-wave
    const int tid = threadIdx.x;
    const int w = tid >> 6, lane = tid & 63, quad = lane >> 4, l16 = lane & 15;
    const int x = blockIdx.x, h = blockIdx.y, b = blockIdx.z;
    // pair-balance: co-resident blocks L and L+256 differ only in b -> qt sums constant
    const int qt = b ? x : (gridDim.x - 1 - x);
    const int q0 = qt * 128;
    const int nkt = 2 * qt + 2;
    const int hkv = h >> 2;
    const ushort_t* Kg = Kr + ((size_t)(b * NKV + hkv) * SEQ) * HD;
    const ushort_t* Vg = Vt + ((size_t)(b * NKV + hkv) * HD) * SEQ;

    // staging addresses (swizzled global chunk)
    const int p = lane >> 2;
    const int gc8 = (((lane & 3) ^ ((lane >> 3) & 3)) << 3);
    const ushort_t* kst = Kg + (size_t)p * HD + w * 32 + gc8;
    const ushort_t* vst = Vg + (size_t)((w & 1) * 64 + p) * SEQ + (w >> 1) * 32 + gc8;
    ushort_t* ksl = Ksh + w * 2048;
    ushort_t* vsl = Vsh + (w >> 1) * 4096 + (w & 1) * 2048;

    auto stage = [&](int bi, int kv0) {
        const ushort_t* gk = kst + (size_t)kv0 * HD;
        ushort_t* lk = ksl + bi * 8192;
        load_lds16(gk, lk);
        load_lds16(gk + (size_t)16 * HD, lk + 512);
        load_lds16(gk + (size_t)32 * HD, lk + 1024);
        load_lds16(gk + (size_t)48 * HD, lk + 1536);
        const ushort_t* gv = vst + kv0;
        ushort_t* lv = vsl + bi * 8192;
        load_lds16(gv, lv);
        load_lds16(gv + (size_t)16 * SEQ, lv + 512);
        load_lds16(gv + (size_t)32 * SEQ, lv + 1024);
        load_lds16(gv + (size_t)48 * SEQ, lv + 1536);
    };

    // Q fragments in registers: 2 subtiles x 4 k-chunks
    bf16x8 aq[2][4];
#pragma unroll
    for (int st = 0; st < 2; st++) {
        const size_t qrow = ((size_t)(b * NH + h) * SEQ + q0 + st * 64 + w * 16 + l16) * HD;
#pragma unroll
        for (int kc = 0; kc < 4; kc++)
            aq[st][kc] = *(const bf16x8*)&Qr[qrow + kc * 32 + quad * 8];
    }

    f32x4 o[2][8];
#pragma unroll
    for (int st = 0; st < 2; st++)
#pragma unroll
        for (int j = 0; j < 8; j++)
#pragma unroll
            for (int e = 0; e < 4; e++) o[st][j][e] = 0.0f;
    f32x4 ls2[2];
#pragma unroll
    for (int st = 0; st < 2; st++)
        for (int e = 0; e < 4; e++) ls2[st][e] = 0.0f;
    bf16x8 ones;
#pragma unroll
    for (int e = 0; e < 8; e++) ones[e] = (short)0x3F80;  // bf16 1.0

    ushort_t* Pw = &Ps[w * 16 * 72];
    const int rsw8 = ((l16 >> 1) & 3) << 3;  // reader swizzle (shorts), XOR with quad*8

    stage(0, 0);
    __syncthreads();  // buf0 staged

    for (int kt = 0; kt < nkt; kt++) {
        const int kv0 = kt * 64;
        const int cur = kt & 1;
        if (kt + 1 < nkt) stage(cur ^ 1, kv0 + 64);  // async prefetch next tile

        const ushort_t* Kb = Ksh + cur * 8192;
        const ushort_t* Vb = Vsh + cur * 8192;

#pragma unroll
        for (int st = 0; st < 2; st++) {
            // subtile 0 is fully masked on the last (odd-diagonal) tile
            if (st == 0 && kt == 2 * qt + 1) continue;

            // QK^T
            f32x4 sa[4];
#pragma unroll
            for (int nt = 0; nt < 4; nt++)
#pragma unroll
                for (int e = 0; e < 4; e++) sa[nt][e] = 0.0f;
#pragma unroll
            for (int kc = 0; kc < 4; kc++) {
#pragma unroll
                for (int nt = 0; nt < 4; nt++) {
                    bf16x8 bk = *(const bf16x8*)&Kb[kc * 2048 + nt * 512 + l16 * 32 +
                                                    ((quad * 8) ^ rsw8)];
                    sa[nt] = mfma16(aq[st][kc], bk, sa[nt]);
                }
            }

            // causal mask on the diagonal tile of this subtile
            if ((kt >> 1) == qt && (kt & 1) == st) {
#pragma unroll
                for (int nt = 0; nt < 4; nt++)
#pragma unroll
                    for (int r = 0; r < 4; r++) {
                        int kvg = kv0 + nt * 16 + l16;
                        int qg = q0 + st * 64 + w * 16 + quad * 4 + r;
                        if (kvg > qg) sa[nt][r] = -1e30f;
                    }
            }

            // P = exp(s), bf16-truncate, per-wave LDS round-trip (C-layout -> A-layout)
#pragma unroll
            for (int nt = 0; nt < 4; nt++)
#pragma unroll
                for (int r = 0; r < 4; r++)
                    Pw[(quad * 4 + r) * 72 + nt * 16 + l16] = f2bf_trunc(__expf(sa[nt][r]));

            // PV
#pragma unroll
            for (int kc = 0; kc < 2; kc++) {
                bf16x8 ap = *(const bf16x8*)&Pw[l16 * 72 + kc * 32 + quad * 8];
                ls2[st] = mfma16(ap, ones, ls2[st]);  // row sums
#pragma unroll
                for (int j = 0; j < 8; j++) {
                    bf16x8 bv = *(const bf16x8*)&Vb[kc * 4096 + (j * 16 + l16) * 32 +
                                                    ((quad * 8) ^ rsw8)];
                    o[st][j] = mfma16(ap, bv, o[st][j]);
                }
            }
        }
        __syncthreads();  // drains prefetch + guards buffer reuse
    }

#pragma unroll
    for (int st = 0; st < 2; st++)
#pragma unroll
        for (int r = 0; r < 4; r++) {
            float inv = 1.0f / ls2[st][r];
            int row = b * SEQ + q0 + st * 64 + w * 16 + quad * 4 + r;
            size_t obase = (size_t)row * HIDDEN + h * HD;
#pragma unroll
            for (int j = 0; j < 8; j++) Attn[obase + j * 16 + l16] = f2bf(o[st][j][r] * inv);
        }
}

extern "C" void kernel_launch(void* const* d_in, const int* in_sizes, int n_in,
                              void* d_out, int out_size, void* d_ws, size_t ws_size,
                              hipStream_t stream) {
    const float* hs = (const float*)d_in[0];
    const int* posids = (const int*)d_in[1];
    const float* Wq = (const float*)d_in[2];
    const float* bq = (const float*)d_in[3];
    const float* Wk = (const float*)d_in[4];
    const float* bk = (const float*)d_in[5];
    const float* Wv = (const float*)d_in[6];
    const float* bv = (const float*)d_in[7];
    const float* Wo = (const float*)d_in[8];
    const float* bo = (const float*)d_in[9];
    float* out = (float*)d_out;

    char* ws = (char*)d_ws;
    size_t off = 0;
    auto alloc = [&](size_t bytes) {
        char* p = ws + off;
        off += (bytes + 255) & ~(size_t)255;
        return p;
    };
    ushort_t* Xb     = (ushort_t*)alloc(4096ull * 2048 * 2);
    ushort_t* WqkvT  = (ushort_t*)alloc(3072ull * 2048 * 2);  // rows: 0..2047 Wq^T | 2048..2559 Wk^T | 2560..3071 Wv^T
    ushort_t* WoT    = (ushort_t*)alloc(2048ull * 2048 * 2);
    ushort_t* Qr     = (ushort_t*)alloc((size_t)BATCH * NH * SEQ * HD * 2);
    ushort_t* Kr     = (ushort_t*)alloc((size_t)BATCH * NKV * SEQ * HD * 2);
    ushort_t* Vtr    = (ushort_t*)alloc((size_t)BATCH * NKV * HD * SEQ * 2);
    ushort_t* Attn   = (ushort_t*)alloc(4096ull * 2048 * 2);

    convert_x<<<4096 * 2048 / 4 / 256, 256, 0, stream>>>(hs, Xb, 4096 * 2048 / 4);
    transpose_all<<<dim3(32, 32, 4), 256, 0, stream>>>(Wq, Wk, Wv, Wo, WqkvT, WoT);

    gemm_bt<2, 32><<<dim3(24, 32), 256, 0, stream>>>(Xb, WqkvT, bq, bk, bv,
                                                     Qr, Kr, Vtr, 4096, 3072, 2048, posids);

    flash<<<dim3(SEQ / 128, NH, BATCH), 256, 0, stream>>>(Qr, Kr, Vtr, Attn);

    gemm_bt<0, 64><<<dim3(16, 32), 256, 0, stream>>>(Attn, WoT, bo, nullptr, nullptr,
                                                     out, nullptr, nullptr, 4096, 2048, 2048, nullptr);
}